// Round 1
// 712.369 us; speedup vs baseline: 1.2436x; 1.2436x over previous
//
#include <hip/hip_runtime.h>
#include <hip/hip_bf16.h>

#define N_USERS 20000
#define N_ITEMS 30000
#define NTOT    50000
#define DIM     64
#define EXTRA_D 1152
#define E_EDGES 500000
#define NC      100
#define KTOT    1216
#define KSTEPS  38
#define PPART   16

#define FEI_BLKS 128
#define CEI_BLKS 64
#define FILL_BLKS ((E_EDGES+255)/256)
#define DEG_BLKS ((NTOT+3)/4)

typedef __attribute__((ext_vector_type(8))) short short8;
typedef __attribute__((ext_vector_type(4))) float v4f;

// ---------------- helpers ----------------
__device__ __forceinline__ float wred_sum(float v){
#pragma unroll
  for(int o=32;o;o>>=1) v += __shfl_xor(v,o,64);
  return v;
}
__device__ __forceinline__ int wred_sumi(int v){
#pragma unroll
  for(int o=32;o;o>>=1) v += __shfl_xor(v,o,64);
  return v;
}
__device__ __forceinline__ float lrelu(float x){ return x>0.f? x : 0.2f*x; }
__device__ __forceinline__ short f2bf(float f){
  unsigned u=__float_as_uint(f);
  unsigned r=(u + 0x7FFFu + ((u>>16)&1u))>>16;
  return (short)r;
}

// ---------------- fused prep: copy_user + prep_w1 + prep_w2 + ccnt ----------------
__global__ __launch_bounds__(256) void prep_misc_kernel(
    const float* __restrict__ u, float* __restrict__ X,
    const float* __restrict__ w1, short* __restrict__ w1t,
    const float* __restrict__ w2, short* __restrict__ w2t,
    const int* __restrict__ ca, int* __restrict__ ccnt)
{
  __shared__ int hist[NC];
  const int b=blockIdx.x, t=threadIdx.x;
  if(b < 1250){
    int i = b*256+t;                       // 1250*256 == N_USERS*64/4 exactly
    ((float4*)X)[i] = ((const float4*)u)[i];
  } else if(b < 1858){
    int i = (b-1250)*256+t;                // 608*256 == KSTEPS*4096 exactly
    int s = i>>12, rem = i&4095, n = rem>>5, kk = rem&31;
    w1t[i] = f2bf(w1[(s*32+kk)*128 + n]);
  } else if(b < 1890){
    int i = (b-1858)*256+t;                // 32*256 == 8192 exactly
    int c = i>>7, n = i&127;
    w2t[i] = f2bf(w2[n*64+c]);
  } else {
    for(int i=t;i<NC;i+=256) hist[i]=0;
    __syncthreads();
    for(int n=(b-1890)*256+t; n<NTOT; n+=64*256) atomicAdd(&hist[ca[n]],1);
    __syncthreads();
    for(int i=t;i<NC;i+=256) if(hist[i]) atomicAdd(&ccnt[i],hist[i]);
  }
}

// ---------------- fused fusion MLP (MFMA bf16) ----------------
__global__ __launch_bounds__(256) void fusion_mfma_kernel(
    const float* __restrict__ item, const float* __restrict__ extra,
    const short* __restrict__ w1t, const float* __restrict__ b1,
    const short* __restrict__ w2t, const float* __restrict__ b2,
    float* __restrict__ X)
{
  __shared__ short As[128*40];
  __shared__ short Bs[128*40];
  __shared__ short Hs[128*136];
  const int tid = threadIdx.x;
  const int blk = blockIdx.x;
  const int w = tid>>6, lane = tid&63, quad = lane>>4, l16 = lane&15;
  const int mw = w&1, nw = w>>1;

  v4f acc[4][4];
#pragma unroll
  for(int a=0;a<4;a++)
#pragma unroll
    for(int b=0;b<4;b++) acc[a][b] = (v4f){0.f,0.f,0.f,0.f};

  const int arow = tid>>3;
  const int aoff = (tid&7)*4;
  for(int s=0;s<KSTEPS;s++){
    const int k0 = s*32;
#pragma unroll
    for(int it=0;it<4;it++){
      int r = arow + it*32;
      int col = k0 + aoff;
      int gr = blk*128 + r; if(gr >= N_ITEMS) gr = N_ITEMS-1;
      float4 v = (col < DIM) ? *(const float4*)(item + (size_t)gr*DIM + col)
                             : *(const float4*)(extra + (size_t)gr*EXTRA_D + (col-DIM));
      short4 bv; bv.x=f2bf(v.x); bv.y=f2bf(v.y); bv.z=f2bf(v.z); bv.w=f2bf(v.w);
      *(short4*)&As[r*40 + aoff] = bv;
    }
#pragma unroll
    for(int it=0;it<2;it++){
      int idx = tid + it*256;
      int4 v = *(const int4*)(w1t + (size_t)s*4096 + idx*8);
      int n = idx>>2, kk = (idx&3)*8;
      *(int4*)&Bs[n*40 + kk] = v;
    }
    __syncthreads();
    short8 af[4], bf_[4];
#pragma unroll
    for(int i=0;i<4;i++){
      int m = mw*64 + i*16 + l16;
      af[i]  = *(const short8*)&As[m*40 + quad*8];
      int n = nw*64 + i*16 + l16;
      bf_[i] = *(const short8*)&Bs[n*40 + quad*8];
    }
#pragma unroll
    for(int mi=0;mi<4;mi++)
#pragma unroll
      for(int ni=0;ni<4;ni++)
        acc[mi][ni] = __builtin_amdgcn_mfma_f32_16x16x32_bf16(af[mi], bf_[ni], acc[mi][ni], 0,0,0);
    __syncthreads();
  }

#pragma unroll
  for(int ni=0;ni<4;ni++){
    int n = nw*64 + ni*16 + l16;
    float bias = b1[n];
#pragma unroll
    for(int mi=0;mi<4;mi++){
      int mbase = mw*64 + mi*16 + quad*4;
#pragma unroll
      for(int r=0;r<4;r++){
        float hv = fmaxf(acc[mi][ni][r] + bias, 0.f);
        Hs[(mbase+r)*136 + n] = f2bf(hv);
      }
    }
  }
  __syncthreads();

  v4f acc2[2][4];
#pragma unroll
  for(int a=0;a<2;a++)
#pragma unroll
    for(int b=0;b<4;b++) acc2[a][b] = (v4f){0.f,0.f,0.f,0.f};
#pragma unroll
  for(int ks=0;ks<4;ks++){
    short8 ha[2];
#pragma unroll
    for(int mi=0;mi<2;mi++){
      int m = w*32 + mi*16 + l16;
      ha[mi] = *(const short8*)&Hs[m*136 + ks*32 + quad*8];
    }
#pragma unroll
    for(int ni=0;ni<4;ni++){
      int c = ni*16 + l16;
      short8 wb = *(const short8*)(w2t + c*128 + ks*32 + quad*8);
#pragma unroll
      for(int mi=0;mi<2;mi++)
        acc2[mi][ni] = __builtin_amdgcn_mfma_f32_16x16x32_bf16(ha[mi], wb, acc2[mi][ni], 0,0,0);
    }
  }
#pragma unroll
  for(int ni=0;ni<4;ni++){
    int c = ni*16 + l16;
    float b2v = b2[c];
#pragma unroll
    for(int mi=0;mi<2;mi++){
      int mbase = w*32 + mi*16 + quad*4;
#pragma unroll
      for(int r=0;r<4;r++){
        int row = blk*128 + mbase + r;
        if(row < N_ITEMS) X[(size_t)(N_USERS+row)*64 + c] = acc2[mi][ni][r] + b2v;
      }
    }
  }
}

// ---------------- fused edge pass: count_dst + clflag + fea sums | cei hist + cea sums ----------------
__global__ __launch_bounds__(256) void edge_pass_kernel(
    const int* __restrict__ fei, const float* __restrict__ fea, const int* __restrict__ ca,
    int* __restrict__ cnt_dst, int* __restrict__ clflag, float2* __restrict__ partA,
    const int* __restrict__ cei, const float* __restrict__ cea, int Ec,
    int* __restrict__ ccnt_dst, float2* __restrict__ partB)
{
  __shared__ int hist[NC];
  __shared__ float2 w4[4];
  const int b=blockIdx.x, t=threadIdx.x;
  const int lane=t&63, wv=t>>6;
  if(b < FEI_BLKS){
    float a0=0.f,a1=0.f;
    for(int e=b*256+t; e<E_EDGES; e+=FEI_BLKS*256){
      int s=fei[e], d=fei[E_EDGES+e];
      atomicAdd(&cnt_dst[d],1);
      int cs=ca[s];
      if(cs==ca[d]) clflag[cs]=1;
      float2 v=*(const float2*)(fea+2*e);
      a0+=v.x; a1+=v.y;
    }
    a0=wred_sum(a0); a1=wred_sum(a1);
    if(lane==0) w4[wv]=make_float2(a0,a1);
    __syncthreads();
    if(t==0){ float2 r=w4[0]; for(int i=1;i<4;i++){r.x+=w4[i].x; r.y+=w4[i].y;} partA[b]=r; }
  } else {
    int bb=b-FEI_BLKS;
    for(int i=t;i<NC;i+=256) hist[i]=0;
    __syncthreads();
    float a0=0.f,a1=0.f;
    for(int e=bb*256+t; e<Ec; e+=CEI_BLKS*256){
      atomicAdd(&hist[cei[Ec+e]],1);
      float2 v=*(const float2*)(cea+2*e);
      a0+=v.x; a1+=v.y;
    }
    a0=wred_sum(a0); a1=wred_sum(a1);
    if(lane==0) w4[wv]=make_float2(a0,a1);
    __syncthreads();
    if(t==0){ float2 r=w4[0]; for(int i=1;i<4;i++){r.x+=w4[i].x; r.y+=w4[i].y;} partB[bb]=r; }
    for(int i=t;i<NC;i+=256) if(hist[i]) atomicAdd(&ccnt_dst[i],hist[i]);
  }
}

// coefs layout: [4]=mean_ea0 [5]=mean_ea1 [6]=mean_cea0 [7]=mean_cea1
//               [8+h]=cgA0[h] [12+h]=cgA1[h] (h<4)
//               [16+l*2+h]=A0[l][h] [20+l*2+h]=A1[l][h] (l<2,h<2)
__global__ void prep_small_kernel(const float2* __restrict__ partA, const float2* __restrict__ partB,
    int Ec,
    const float* __restrict__ cg_le, const float* __restrict__ cg_ae,
    const float* __restrict__ gat_le, const float* __restrict__ gat_ae,
    float* __restrict__ coefs)
{
  int tid=threadIdx.x; int lane=tid&63; int wv=tid>>6;
  {
    int hh=wv;
    float v0 = cg_le[hh*64+lane]*cg_ae[hh*64+lane];
    float v1 = cg_le[256 + hh*64+lane]*cg_ae[hh*64+lane];
    v0=wred_sum(v0); v1=wred_sum(v1);
    if(lane==0){ coefs[8+hh]=v0; coefs[12+hh]=v1; }
  }
  {
    int l=wv>>1, hh=wv&1;
    float v0 = gat_le[l*256 + hh*64+lane]     * gat_ae[l*128+hh*64+lane];
    float v1 = gat_le[l*256 + 128 + hh*64+lane]* gat_ae[l*128+hh*64+lane];
    v0=wred_sum(v0); v1=wred_sum(v1);
    if(lane==0){ coefs[16+l*2+hh]=v0; coefs[20+l*2+hh]=v1; }
  }
  __syncthreads();
  if(wv==0){
    float2 v=partA[lane], v2=partA[64+lane];
    float sx=wred_sum(v.x+v2.x), sy=wred_sum(v.y+v2.y);
    if(lane==0){ coefs[4]=sx/(float)E_EDGES; coefs[5]=sy/(float)E_EDGES; }
  }
  if(wv==1){
    float2 v=partB[lane];
    float sx=wred_sum(v.x), sy=wred_sum(v.y);
    if(lane==0){ coefs[6]=sx/(float)Ec; coefs[7]=sy/(float)Ec; }
  }
}

// ---------------- CSR scans ----------------
__global__ __launch_bounds__(1024) void scan1_kernel(const int* __restrict__ cnt,
    int* __restrict__ incl, int* __restrict__ bsum){
  __shared__ int s[1024];
  int i = blockIdx.x*1024 + threadIdx.x;
  int v = (i<NTOT)? cnt[i]+1 : 0;
  s[threadIdx.x]=v; __syncthreads();
  for(int off=1; off<1024; off<<=1){
    int t = (threadIdx.x>=off)? s[threadIdx.x-off] : 0;
    __syncthreads();
    s[threadIdx.x]+=t;
    __syncthreads();
  }
  if(i<NTOT) incl[i]=s[threadIdx.x];
  if(threadIdx.x==1023) bsum[blockIdx.x]=s[1023];
}
// block 0: scan of bsum (full-graph) ; block 1: cluster-CSR scan
__global__ void small_scans_kernel(int* __restrict__ bsum, int nb,
    const int* __restrict__ ccnt_dst, int* __restrict__ coffs, int* __restrict__ cfillp){
  int lane=threadIdx.x;
  if(blockIdx.x==0){
    int v = (lane<nb)? bsum[lane]:0;
#pragma unroll
    for(int o=1;o<64;o<<=1){ int t=__shfl_up(v,o,64); if(lane>=o) v+=t; }
    if(lane<nb) bsum[lane]=v;
  } else {
    int v0 = (2*lane<NC)? ccnt_dst[2*lane]:0;
    int v1 = (2*lane+1<NC)? ccnt_dst[2*lane+1]:0;
    int pair=v0+v1;
    int sc=pair;
#pragma unroll
    for(int o=1;o<64;o<<=1){ int t2=__shfl_up(sc,o,64); if(lane>=o) sc+=t2; }
    int excl = sc - pair;
    if(2*lane<NC){ coffs[2*lane]=excl; cfillp[2*lane]=excl; }
    if(2*lane+1<NC){ coffs[2*lane+1]=excl+v0; cfillp[2*lane+1]=excl+v0; }
    if(lane==63) coffs[NC]=sc;
  }
}
// scan3 also writes the self-loop slot directly at start+cnt (deterministic position)
__global__ void scan3_kernel(const int* __restrict__ incl, const int* __restrict__ cnt,
    const int* __restrict__ bsum, int* __restrict__ offs, int* __restrict__ fillptr,
    const float* __restrict__ coefs, int4* __restrict__ slot){
  int i=blockIdx.x*256+threadIdx.x;
  if(i<NTOT){
    int blk=i>>10;
    int prev = blk? bsum[blk-1]:0;
    int c=cnt[i];
    int start = prev + incl[i] - (c+1);
    offs[i]=start; fillptr[i]=start;
    slot[start+c]=make_int4(i,__float_as_int(coefs[4]),__float_as_int(coefs[5]),0);
  }
  if(i==0) offs[NTOT]=E_EDGES+NTOT;
}
// fused: full-graph edge fill + cluster-edge fill
__global__ __launch_bounds__(256) void fill_both_kernel(
    const int* __restrict__ fei, const float* __restrict__ fea,
    int* __restrict__ fillptr, int4* __restrict__ slot,
    const int* __restrict__ cei, const float* __restrict__ cea, int Ec,
    int* __restrict__ cfillp, int* __restrict__ cslot_src, float2* __restrict__ cslot_ea)
{
  __shared__ int hist[NC];
  __shared__ int base[NC];
  const int b=blockIdx.x, t=threadIdx.x;
  if(b<FILL_BLKS){
    int e=b*256+t;
    if(e<E_EDGES){
      int dst=fei[E_EDGES+e], src=fei[e];
      int pos=atomicAdd(&fillptr[dst],1);
      float2 v=*(const float2*)(fea+2*e);
      slot[pos]=make_int4(src,__float_as_int(v.x),__float_as_int(v.y),0);
    }
  } else {
    int bb=b-FILL_BLKS;
    const int chunk=(Ec+127)/128;
    const int beg=bb*chunk;
    const int end=min(beg+chunk,Ec);
    for(int i=t;i<NC;i+=256) hist[i]=0;
    __syncthreads();
    for(int e=beg+t;e<end;e+=256) atomicAdd(&hist[cei[Ec+e]],1);
    __syncthreads();
    for(int i=t;i<NC;i+=256){
      int h=hist[i];
      base[i] = h ? atomicAdd(&cfillp[i],h) : 0;
      hist[i]=0;
    }
    __syncthreads();
    for(int e=beg+t;e<end;e+=256){
      int d=cei[Ec+e];
      int pos = base[d] + atomicAdd(&hist[d],1);
      cslot_src[pos]=cei[e];
      cslot_ea[pos]=make_float2(cea[2*e],cea[2*e+1]);
    }
  }
}

// ---------------- GCN: fused deg + xw ----------------
__global__ __launch_bounds__(256) void gcn_pre_kernel(const int* __restrict__ offs,
    const int4* __restrict__ slot, const int* __restrict__ ca, float* __restrict__ dinv,
    const float* __restrict__ X, const float* __restrict__ gw, float* __restrict__ xw){
  __shared__ float Wl[64*64];
  __shared__ float rowb[4][64];
  const int b=blockIdx.x;
  const int lane=threadIdx.x&63, wv=threadIdx.x>>6;
  if(b<DEG_BLKS){
    int n = b*4+wv; if(n>=NTOT) return;
    int beg=offs[n], end=offs[n+1], myca=ca[n];
    int c=0;
    for(int j=beg+lane;j<end;j+=64) c += (ca[slot[j].x]==myca)?1:0;
    c = wred_sumi(c);
    if(lane==0) dinv[n]=rsqrtf((float)c);
  } else {
    int bb=b-DEG_BLKS;
    for(int i=threadIdx.x;i<4096;i+=256) Wl[i]=gw[i];
    __syncthreads();
    for(int r=bb*4+wv; r<NTOT; r+=1024*4){
      rowb[wv][lane]=X[(size_t)r*64+lane];
      float acc=0.f;
#pragma unroll 8
      for(int k=0;k<64;k++) acc+=rowb[wv][k]*Wl[k*64+lane];
      xw[(size_t)r*64+lane]=acc;
    }
  }
}
// staged + ballot-sparse inner loop (only ~1% of edges are intra-cluster)
__global__ __launch_bounds__(256) void gcn_agg_kernel(const float* __restrict__ X,
    const float* __restrict__ xw, const float* __restrict__ gcn_b,
    const int* __restrict__ offs, const int4* __restrict__ slot, const int* __restrict__ ca,
    const float* __restrict__ dinv, const int* __restrict__ flag,
    float* __restrict__ Xc, float* __restrict__ psum){
  __shared__ float2 stg[4][64];
  int lane=threadIdx.x&63, wv=threadIdx.x>>6;
  int n=blockIdx.x*4+wv; if(n>=NTOT) return;
  int beg=offs[n], end=offs[n+1], myca=ca[n];
  float acc=0.f;
  for(int c0=beg;c0<end;c0+=64){
    int j=c0+lane;
    float coef=0.f; int s=0;
    if(j<end){
      s=slot[j].x;
      if(ca[s]==myca) coef=dinv[s];
    }
    stg[wv][lane]=make_float2(__int_as_float(s),coef);
    unsigned long long bal=__ballot(coef!=0.f);
    while(bal){
      int k=__builtin_ctzll(bal); bal&=bal-1;
      float2 sc=stg[wv][k];
      acc += sc.y * xw[(size_t)__float_as_int(sc.x)*64+lane];
    }
  }
  float gout = dinv[n]*acc + gcn_b[lane];
  float xc = flag[myca] ? gout : X[(size_t)n*64+lane];
  Xc[(size_t)n*64+lane]=xc;
  atomicAdd(&psum[(size_t)(blockIdx.x&(PPART-1))*NC*64 + myca*64+lane], xc);
}

// ---------------- cluster GAT prep: pooled_fin + xhc + attc fused ----------------
__global__ __launch_bounds__(256) void cluster_prep_kernel(const float* __restrict__ psum,
    const int* __restrict__ ccnt, const float* __restrict__ cg_lin,
    const float* __restrict__ as_, const float* __restrict__ ad_,
    float* __restrict__ xh_c, float* __restrict__ asrc_c, float* __restrict__ adst_c){
  __shared__ float prow[64];
  const int c=blockIdx.x, t=threadIdx.x;
  if(t<64){
    float a=0.f;
#pragma unroll
    for(int p=0;p<PPART;p++) a += psum[(size_t)p*NC*64 + c*64 + t];
    prow[t]=a/fmaxf((float)ccnt[c],1.f);
  }
  __syncthreads();
  float acc=0.f;
#pragma unroll 8
  for(int k=0;k<64;k++) acc += prow[k]*cg_lin[k*256+t];
  xh_c[c*256+t]=acc;
  int lane=t&63, hh=t>>6;
  float s=wred_sum(acc*as_[hh*64+lane]);
  float d=wred_sum(acc*ad_[hh*64+lane]);
  if(lane==0){ asrc_c[c*4+hh]=s; adst_c[c*4+hh]=d; }
}
// single-pass softmax (no max subtraction: logits O(1), exp cannot overflow)
__global__ __launch_bounds__(256) void cluster_agg_kernel(
    const int* __restrict__ coffs, const int* __restrict__ cslot_src, const float2* __restrict__ cslot_ea,
    const float* __restrict__ asrc_c, const float* __restrict__ adst_c, const float* __restrict__ coefs,
    const float* __restrict__ xh_c, const float* __restrict__ cg_bias, float* __restrict__ cl_upd)
{
  __shared__ float sas[NC*4];
  __shared__ float sW[NC*4];
  __shared__ float ssum[4];
  __shared__ float red[4][64];
  const int c=blockIdx.x, t=threadIdx.x;
  for(int i=t;i<NC*4;i+=256){ sas[i]=asrc_c[i]; sW[i]=0.f; }
  __syncthreads();
  float ad[4], A0[4], A1[4];
#pragma unroll
  for(int h=0;h<4;h++){ ad[h]=adst_c[c*4+h]; A0[h]=coefs[8+h]; A1[h]=coefs[12+h]; }
  const int beg=coffs[c], end=coffs[c+1];
  for(int j=beg+t;j<end;j+=256){
    int s=cslot_src[j]; float2 e=cslot_ea[j];
#pragma unroll
    for(int h=0;h<4;h++){
      float al=lrelu(sas[s*4+h]+ad[h]+e.x*A0[h]+e.y*A1[h]);
      atomicAdd(&sW[s*4+h], expf(al));
    }
  }
  if(t<4){
    float al=lrelu(sas[c*4+t]+ad[t]+coefs[6]*A0[t]+coefs[7]*A1[t]);
    atomicAdd(&sW[c*4+t], expf(al));
  }
  __syncthreads();
  const int h=t>>6, lane=t&63;
  float p=0.f;
  if(lane<NC)    p += sW[lane*4+h];
  if(lane+64<NC) p += sW[(lane+64)*4+h];
  p=wred_sum(p);
  if(lane==0) ssum[h]=p+1e-16f;
  __syncthreads();
  float inv=1.f/ssum[h];
  float acc=0.f;
  for(int s=0;s<NC;s++) acc += sW[s*4+h]*xh_c[s*256+h*64+lane];
  red[h][lane]=acc*inv;
  __syncthreads();
  if(t<64) cl_upd[c*64+t]=0.25f*(red[0][t]+red[1][t]+red[2][t]+red[3][t])+cg_bias[t];
}

// ---------------- GAT layer 0 xh: fused xcomb (Xc + cl_upd[ca]) ----------------
__global__ __launch_bounds__(256) void gat_xh0_kernel(const float* __restrict__ Xc,
    const float* __restrict__ cl_upd, const int* __restrict__ ca,
    const float* __restrict__ lin, const float* __restrict__ att_s, const float* __restrict__ att_d,
    float2* __restrict__ xh2, float* __restrict__ asrc, float* __restrict__ adst,
    float* __restrict__ Xa){
  __shared__ __align__(16) float Wl[64*128];
  __shared__ float rowb[4][64];
  int t=threadIdx.x;
  for(int i=t;i<8192;i+=256) Wl[i]=lin[i];
  __syncthreads();
  int lane=t&63, wv=t>>6;
  float as0=att_s[lane], as1=att_s[64+lane], ad0=att_d[lane], ad1=att_d[64+lane];
  for(int r=blockIdx.x*4+wv; r<NTOT; r+=gridDim.x*4){
    float xv = Xc[(size_t)r*64+lane] + cl_upd[ca[r]*64+lane];
    Xa[(size_t)r*64+lane]=xv;
    rowb[wv][lane]=xv;
    float x0=0.f,x1=0.f;
#pragma unroll 8
    for(int k=0;k<64;k++){ float q=rowb[wv][k]; x0+=q*Wl[k*128+lane]; x1+=q*Wl[k*128+64+lane]; }
    xh2[(size_t)r*64+lane]=make_float2(x0,x1);
    float p0=wred_sum(x0*as0);
    float p1=wred_sum(x1*as1);
    float q0=wred_sum(x0*ad0);
    float q1=wred_sum(x1*ad1);
    if(lane==0){ asrc[2*r]=p0; asrc[2*r+1]=p1; adst[2*r]=q0; adst[2*r+1]=q1; }
  }
}
// ---------------- GAT layer 1 xh: fused GraphNorm+ELU of layer-0 output ----------------
__global__ __launch_bounds__(256) void gat_xh1_kernel(const float* __restrict__ g,
    const float* __restrict__ Xres, const float* __restrict__ stats,
    const float* __restrict__ gnw, const float* __restrict__ gnb, const float* __restrict__ gnms,
    const float* __restrict__ lin, const float* __restrict__ att_s, const float* __restrict__ att_d,
    float2* __restrict__ xh2, float* __restrict__ asrc, float* __restrict__ adst,
    float* __restrict__ Xb){
  __shared__ __align__(16) float Wl[64*128];
  __shared__ float rowb[4][64];
  int t=threadIdx.x;
  for(int i=t;i<8192;i+=256) Wl[i]=lin[i];
  __syncthreads();
  int lane=t&63, wv=t>>6;
  const float invN = 1.f/(float)NTOT;
  float m=stats[lane]*invN;
  float mm=gnms[lane]*m;
  float gwv=rsqrtf(stats[64+lane]*invN - 2.f*mm*m + mm*mm + 1e-5f)*gnw[lane];
  float gbv=gnb[lane];
  float as0=att_s[lane], as1=att_s[64+lane], ad0=att_d[lane], ad1=att_d[64+lane];
  for(int r=blockIdx.x*4+wv; r<NTOT; r+=gridDim.x*4){
    float z=(g[(size_t)r*64+lane]-mm)*gwv+gbv + Xres[(size_t)r*64+lane];
    float xv = z>0.f? z : expf(z)-1.f;
    Xb[(size_t)r*64+lane]=xv;
    rowb[wv][lane]=xv;
    float x0=0.f,x1=0.f;
#pragma unroll 8
    for(int k=0;k<64;k++){ float q=rowb[wv][k]; x0+=q*Wl[k*128+lane]; x1+=q*Wl[k*128+64+lane]; }
    xh2[(size_t)r*64+lane]=make_float2(x0,x1);
    float p0=wred_sum(x0*as0);
    float p1=wred_sum(x1*as1);
    float q0=wred_sum(x0*ad0);
    float q1=wred_sum(x1*ad1);
    if(lane==0){ asrc[2*r]=p0; asrc[2*r+1]=p1; adst[2*r]=q0; adst[2*r+1]=q1; }
  }
}

// exp once per edge (lane-strided), staged in LDS, gather loop unrolled x4 for MLP
__global__ __launch_bounds__(256) void gat_agg_kernel(const float2* __restrict__ xh2,
    const float2* __restrict__ asrc, const float2* __restrict__ adst,
    const int* __restrict__ offs, const int4* __restrict__ slot,
    const float* __restrict__ coefs, int layer, const float* __restrict__ bias,
    float* __restrict__ g){
  __shared__ float4 stg[4][64];
  int lane=threadIdx.x&63, wv=threadIdx.x>>6;
  int n=blockIdx.x*4+wv; if(n>=NTOT) return;
  float A00=coefs[16+layer*2+0], A01=coefs[16+layer*2+1];
  float A10=coefs[20+layer*2+0], A11=coefs[20+layer*2+1];
  int beg=offs[n], end=offs[n+1];
  float2 adn=adst[n];
  float s0=0.f,s1=0.f,acc0=0.f,acc1=0.f;
  for(int c0=beg;c0<end;c0+=64){
    int j=c0+lane;
    float ex0=0.f,ex1=0.f; int s=0;
    if(j<end){
      int4 sl=slot[j];
      s=sl.x;
      float e0=__int_as_float(sl.y), e1=__int_as_float(sl.z);
      float2 a=asrc[s];
      ex0=expf(lrelu(a.x+adn.x+e0*A00+e1*A10));
      ex1=expf(lrelu(a.y+adn.y+e0*A01+e1*A11));
    }
    s0+=ex0; s1+=ex1;
    stg[wv][lane]=make_float4(__int_as_float(s),ex0,ex1,0.f);
    int cnt=min(64,end-c0);
    int k=0;
    for(; k+4<=cnt; k+=4){
      float4 w0=stg[wv][k], w1=stg[wv][k+1], w2=stg[wv][k+2], w3=stg[wv][k+3];
      float2 x0=xh2[(size_t)__float_as_int(w0.x)*64+lane];
      float2 x1=xh2[(size_t)__float_as_int(w1.x)*64+lane];
      float2 x2=xh2[(size_t)__float_as_int(w2.x)*64+lane];
      float2 x3=xh2[(size_t)__float_as_int(w3.x)*64+lane];
      acc0 += w0.y*x0.x + w1.y*x1.x + w2.y*x2.x + w3.y*x3.x;
      acc1 += w0.z*x0.y + w1.z*x1.y + w2.z*x2.y + w3.z*x3.y;
    }
    for(; k<cnt; k++){
      float4 ws=stg[wv][k];
      float2 xv=xh2[(size_t)__float_as_int(ws.x)*64+lane];
      acc0 += ws.y*xv.x;
      acc1 += ws.z*xv.y;
    }
  }
  s0=wred_sum(s0); s1=wred_sum(s1);
  g[(size_t)n*64+lane]=0.5f*(acc0/(s0+1e-16f)+acc1/(s1+1e-16f))+bias[lane];
}
// GraphNorm stats: float4 loads, per-block shared reduce, direct global atomics (stats pre-zeroed)
__global__ __launch_bounds__(256) void stats_kernel(const float* __restrict__ g,
    float* __restrict__ stats){
  __shared__ float s1[64], s2[64];
  int t=threadIdx.x;
  if(t<64){s1[t]=0.f;s2[t]=0.f;}
  __syncthreads();
  float a0=0.f,a1=0.f,a2=0.f,a3=0.f,b0=0.f,b1=0.f,b2=0.f,b3=0.f;
  int i0=blockIdx.x*256+t;
  for(int i=i0;i<NTOT*16;i+=gridDim.x*256){
    float4 v=((const float4*)g)[i];
    a0+=v.x;a1+=v.y;a2+=v.z;a3+=v.w;
    b0+=v.x*v.x;b1+=v.y*v.y;b2+=v.z*v.z;b3+=v.w*v.w;
  }
  int d0=(i0&15)*4;
  atomicAdd(&s1[d0],a0); atomicAdd(&s1[d0+1],a1); atomicAdd(&s1[d0+2],a2); atomicAdd(&s1[d0+3],a3);
  atomicAdd(&s2[d0],b0); atomicAdd(&s2[d0+1],b1); atomicAdd(&s2[d0+2],b2); atomicAdd(&s2[d0+3],b3);
  __syncthreads();
  if(t<64) atomicAdd(&stats[t],s1[t]);
  else if(t<128) atomicAdd(&stats[t],s2[t-64]);
}
// final GraphNorm+ELU -> out (float4)
__global__ __launch_bounds__(256) void gnorm_elu_kernel(const float* __restrict__ g,
    const float* __restrict__ Xin, const float* __restrict__ stats,
    const float* __restrict__ gw, const float* __restrict__ gb, const float* __restrict__ gms,
    float* __restrict__ outp){
  const float invN = 1.f/(float)NTOT;
  int i0=blockIdx.x*256+threadIdx.x;
  int d0=(i0&15)*4;
  float mmv[4],gwv[4],gbv[4];
#pragma unroll
  for(int j=0;j<4;j++){
    int d=d0+j;
    float m=stats[d]*invN;
    float mm=gms[d]*m;
    mmv[j]=mm;
    gwv[j]=rsqrtf(stats[64+d]*invN-2.f*mm*m+mm*mm+1e-5f)*gw[d];
    gbv[j]=gb[d];
  }
  for(int i=i0;i<NTOT*16;i+=gridDim.x*256){
    float4 gv=((const float4*)g)[i];
    float4 xv=((const float4*)Xin)[i];
    float4 o; float z;
    z=(gv.x-mmv[0])*gwv[0]+gbv[0]+xv.x; o.x = z>0.f? z : expf(z)-1.f;
    z=(gv.y-mmv[1])*gwv[1]+gbv[1]+xv.y; o.y = z>0.f? z : expf(z)-1.f;
    z=(gv.z-mmv[2])*gwv[2]+gbv[2]+xv.z; o.z = z>0.f? z : expf(z)-1.f;
    z=(gv.w-mmv[3])*gwv[3]+gbv[3]+xv.w; o.w = z>0.f? z : expf(z)-1.f;
    ((float4*)outp)[i]=o;
  }
}

// ---------------- launch ----------------
extern "C" void kernel_launch(void* const* d_in, const int* in_sizes, int n_in,
                              void* d_out, int out_size, void* d_ws, size_t ws_size,
                              hipStream_t stream)
{
  const float* extra = (const float*)d_in[0];
  const float* user  = (const float*)d_in[1];
  const float* item  = (const float*)d_in[2];
  const float* fw1 = (const float*)d_in[3];
  const float* fb1 = (const float*)d_in[4];
  const float* fw2 = (const float*)d_in[5];
  const float* fb2 = (const float*)d_in[6];
  const float* fea = (const float*)d_in[7];
  const float* gcn_w = (const float*)d_in[8];
  const float* gcn_b = (const float*)d_in[9];
  const float* cg_lin = (const float*)d_in[10];
  const float* cg_as = (const float*)d_in[11];
  const float* cg_ad = (const float*)d_in[12];
  const float* cg_le = (const float*)d_in[13];
  const float* cg_ae = (const float*)d_in[14];
  const float* cg_bias = (const float*)d_in[15];
  const float* cea = (const float*)d_in[16];
  const float* gat_lin = (const float*)d_in[17];
  const float* gat_as = (const float*)d_in[18];
  const float* gat_ad = (const float*)d_in[19];
  const float* gat_le = (const float*)d_in[20];
  const float* gat_ae = (const float*)d_in[21];
  const float* gat_bias = (const float*)d_in[22];
  const float* gn_w = (const float*)d_in[23];
  const float* gn_b = (const float*)d_in[24];
  const float* gn_ms = (const float*)d_in[25];
  const int* fei = (const int*)d_in[26];
  const int* ca  = (const int*)d_in[27];
  const int* cei = (const int*)d_in[28];
  const int Ec = in_sizes[16]/2;
  float* outp = (float*)d_out;

  char* w = (char*)d_ws;
  auto alloc=[&](size_t b)->char*{ char* p=w; w += (b+255)&~(size_t)255; return p; };

  // zero region (single memset)
  char* z0 = w;
  int* cnt_dst = (int*)alloc((size_t)NTOT*4);
  int* clflag = (int*)alloc(NC*4);
  int* ccnt = (int*)alloc(NC*4);
  int* ccnt_dst = (int*)alloc(NC*4);
  float* psum = (float*)alloc((size_t)PPART*NC*64*4);
  float* stats0 = (float*)alloc(128*4);
  float* stats1 = (float*)alloc(128*4);
  size_t zbytes = (size_t)(w - z0);

  float2* partA = (float2*)alloc(128*8);
  float2* partB = (float2*)alloc(64*8);
  float* coefs = (float*)alloc(32*4);
  int* offs = (int*)alloc((size_t)(NTOT+1)*4);
  int* incl = (int*)alloc((size_t)NTOT*4);
  int* bsum = (int*)alloc(64*4);
  int* fillptr = (int*)alloc((size_t)NTOT*4);
  int4* slot = (int4*)alloc((size_t)(E_EDGES+NTOT)*16);
  int* coffs = (int*)alloc((size_t)(NC+1)*4);
  int* cfillp = (int*)alloc((size_t)NC*4);
  int* cslot_src = (int*)alloc((size_t)E_EDGES*4);
  float2* cslot_ea = (float2*)alloc((size_t)E_EDGES*8);
  float* dinv = (float*)alloc((size_t)NTOT*4);
  float* xh_c = (float*)alloc(NC*256*4);
  float* asrc_c = (float*)alloc(NC*4*4);
  float* adst_c = (float*)alloc(NC*4*4);
  float* cl_upd = (float*)alloc(NC*64*4);
  float* asrc = (float*)alloc((size_t)NTOT*2*4);
  float* adst = (float*)alloc((size_t)NTOT*2*4);
  short* w1t = (short*)alloc((size_t)KSTEPS*4096*2);
  short* w2t = (short*)alloc((size_t)64*128*2);
  float* bufA = (float*)alloc((size_t)NTOT*64*4);   // X, then g
  float* bufB = (float*)alloc((size_t)NTOT*64*4);   // Xc
  float* bufC = (float*)alloc((size_t)NTOT*64*4);   // xw, then Xb
  float* bufD = (float*)alloc((size_t)NTOT*64*4);   // Xa
  float* bufE = (float*)alloc((size_t)NTOT*128*4);  // xh2 (both layers)

  float* X  = bufA; float* g  = bufA;
  float* Xc = bufB;
  float* xw = bufC; float* Xb = bufC;
  float* Xa = bufD;
  float2* xh2 = (float2*)bufE;

  hipMemsetAsync(z0, 0, zbytes, stream);

  prep_misc_kernel<<<1954,256,0,stream>>>(user, X, fw1, w1t, fw2, w2t, ca, ccnt);
  fusion_mfma_kernel<<<(N_ITEMS+127)/128,256,0,stream>>>(item, extra, w1t, fb1, w2t, fb2, X);

  edge_pass_kernel<<<FEI_BLKS+CEI_BLKS,256,0,stream>>>(fei, fea, ca, cnt_dst, clflag, partA,
                                                       cei, cea, Ec, ccnt_dst, partB);
  prep_small_kernel<<<1,256,0,stream>>>(partA, partB, Ec, cg_le, cg_ae, gat_le, gat_ae, coefs);

  scan1_kernel<<<(NTOT+1023)/1024,1024,0,stream>>>(cnt_dst, incl, bsum);
  small_scans_kernel<<<2,64,0,stream>>>(bsum, (NTOT+1023)/1024, ccnt_dst, coffs, cfillp);
  scan3_kernel<<<(NTOT+255)/256,256,0,stream>>>(incl, cnt_dst, bsum, offs, fillptr, coefs, slot);
  fill_both_kernel<<<FILL_BLKS+128,256,0,stream>>>(fei, fea, fillptr, slot,
                                                   cei, cea, Ec, cfillp, cslot_src, cslot_ea);

  gcn_pre_kernel<<<DEG_BLKS+1024,256,0,stream>>>(offs, slot, ca, dinv, X, gcn_w, xw);
  gcn_agg_kernel<<<DEG_BLKS,256,0,stream>>>(X, xw, gcn_b, offs, slot, ca, dinv, clflag, Xc, psum);
  cluster_prep_kernel<<<NC,256,0,stream>>>(psum, ccnt, cg_lin, cg_as, cg_ad, xh_c, asrc_c, adst_c);
  cluster_agg_kernel<<<NC,256,0,stream>>>(coffs, cslot_src, cslot_ea, asrc_c, adst_c, coefs,
                                          xh_c, cg_bias, cl_upd);

  // layer 0 (xcomb fused into xh)
  gat_xh0_kernel<<<1024,256,0,stream>>>(Xc, cl_upd, ca, gat_lin, gat_as, gat_ad,
                                        xh2, asrc, adst, Xa);
  gat_agg_kernel<<<DEG_BLKS,256,0,stream>>>(xh2, (const float2*)asrc, (const float2*)adst,
                                            offs, slot, coefs, 0, gat_bias, g);
  stats_kernel<<<128,256,0,stream>>>(g, stats0);
  // layer 1 (GraphNorm+ELU of layer 0 fused into xh)
  gat_xh1_kernel<<<1024,256,0,stream>>>(g, Xa, stats0, gn_w, gn_b, gn_ms,
                                        gat_lin+64*128, gat_as+128, gat_ad+128,
                                        xh2, asrc, adst, Xb);
  gat_agg_kernel<<<DEG_BLKS,256,0,stream>>>(xh2, (const float2*)asrc, (const float2*)adst,
                                            offs, slot, coefs, 1, gat_bias+64, g);
  stats_kernel<<<128,256,0,stream>>>(g, stats1);
  gnorm_elu_kernel<<<512,256,0,stream>>>(g, Xb, stats1, gn_w+64, gn_b+64, gn_ms+64, outp);
}

// Round 2
// 703.226 us; speedup vs baseline: 1.2597x; 1.0130x over previous
//
#include <hip/hip_runtime.h>
#include <hip/hip_bf16.h>

#define N_USERS 20000
#define N_ITEMS 30000
#define NTOT    50000
#define DIM     64
#define EXTRA_D 1152
#define E_EDGES 500000
#define NC      100
#define KTOT    1216
#define KSTEPS  38
#define PPART   16

// prep_all block ranges
#define B_COPY 1250
#define B_W1   608
#define B_W2   32
#define B_CC   64
#define B_FEI  128
#define B_CEI  64
#define PREP_GRID (B_COPY+B_W1+B_W2+B_CC+B_FEI+B_CEI)   // 2146

#define FUS_BLKS ((N_ITEMS+127)/128)     // 235
#define SCAN1_BLKS ((NTOT+1023)/1024)    // 49
#define SC3_BLKS ((NTOT+255)/256)        // 196
#define FILL_BLKS ((E_EDGES+255)/256)    // 1954
#define DEG_BLKS ((NTOT+3)/4)            // 12500

typedef __attribute__((ext_vector_type(8))) short short8;
typedef __attribute__((ext_vector_type(4))) float v4f;

// ---------------- helpers ----------------
__device__ __forceinline__ float wred_sum(float v){
#pragma unroll
  for(int o=32;o;o>>=1) v += __shfl_xor(v,o,64);
  return v;
}
__device__ __forceinline__ int wred_sumi(int v){
#pragma unroll
  for(int o=32;o;o>>=1) v += __shfl_xor(v,o,64);
  return v;
}
__device__ __forceinline__ float lrelu(float x){ return x>0.f? x : 0.2f*x; }
__device__ __forceinline__ short f2bf(float f){
  unsigned u=__float_as_uint(f);
  unsigned r=(u + 0x7FFFu + ((u>>16)&1u))>>16;
  return (short)r;
}
__device__ __forceinline__ unsigned pack_bf2(float x, float y){
  return (unsigned)(unsigned short)f2bf(x) | ((unsigned)(unsigned short)f2bf(y)<<16);
}

// ---------------- K2: prep_all ----------------
// user copy | w1 transpose->bf16 | w2 transpose->bf16 | cluster node hist |
// fei pass (cnt_dst + clflag + intra-deg + fea sums) | cei pass (hist + cea sums)
__global__ __launch_bounds__(256) void prep_all_kernel(
    const float* __restrict__ u, float* __restrict__ X,
    const float* __restrict__ w1, short* __restrict__ w1t,
    const float* __restrict__ w2, short* __restrict__ w2t,
    const int* __restrict__ ca, int* __restrict__ ccnt,
    const int* __restrict__ fei, const float* __restrict__ fea,
    int* __restrict__ cnt_dst, int* __restrict__ clflag, int* __restrict__ degI,
    float2* __restrict__ partA,
    const int* __restrict__ cei, const float* __restrict__ cea, int Ec,
    int* __restrict__ ccnt_dst, float2* __restrict__ partB)
{
  __shared__ int hist[NC];
  __shared__ float2 w4[4];
  const int b=blockIdx.x, t=threadIdx.x;
  const int lane=t&63, wv=t>>6;
  if(b < B_COPY){
    int i = b*256+t;                       // 1250*256 == N_USERS*64/4 exactly
    ((float4*)X)[i] = ((const float4*)u)[i];
  } else if(b < B_COPY+B_W1){
    int i = (b-B_COPY)*256+t;              // 608*256 == KSTEPS*4096 exactly
    int s = i>>12, rem = i&4095, n = rem>>5, kk = rem&31;
    w1t[i] = f2bf(w1[(s*32+kk)*128 + n]);
  } else if(b < B_COPY+B_W1+B_W2){
    int i = (b-B_COPY-B_W1)*256+t;         // 32*256 == 8192 exactly
    int c = i>>7, n = i&127;
    w2t[i] = f2bf(w2[n*64+c]);
  } else if(b < B_COPY+B_W1+B_W2+B_CC){
    int bb = b-(B_COPY+B_W1+B_W2);
    for(int i=t;i<NC;i+=256) hist[i]=0;
    __syncthreads();
    for(int n=bb*256+t; n<NTOT; n+=B_CC*256) atomicAdd(&hist[ca[n]],1);
    __syncthreads();
    for(int i=t;i<NC;i+=256) if(hist[i]) atomicAdd(&ccnt[i],hist[i]);
  } else if(b < B_COPY+B_W1+B_W2+B_CC+B_FEI){
    int bb = b-(B_COPY+B_W1+B_W2+B_CC);
    float a0=0.f,a1=0.f;
    for(int e=bb*256+t; e<E_EDGES; e+=B_FEI*256){
      int s=fei[e], d=fei[E_EDGES+e];
      atomicAdd(&cnt_dst[d],1);
      int cs=ca[s];
      if(cs==ca[d]){ clflag[cs]=1; atomicAdd(&degI[d],1); }
      float2 v=*(const float2*)(fea+2*e);
      a0+=v.x; a1+=v.y;
    }
    a0=wred_sum(a0); a1=wred_sum(a1);
    if(lane==0) w4[wv]=make_float2(a0,a1);
    __syncthreads();
    if(t==0){ float2 r=w4[0]; for(int i=1;i<4;i++){r.x+=w4[i].x; r.y+=w4[i].y;} partA[bb]=r; }
  } else {
    int bb = b-(B_COPY+B_W1+B_W2+B_CC+B_FEI);
    for(int i=t;i<NC;i+=256) hist[i]=0;
    __syncthreads();
    float a0=0.f,a1=0.f;
    for(int e=bb*256+t; e<Ec; e+=B_CEI*256){
      atomicAdd(&hist[cei[Ec+e]],1);
      float2 v=*(const float2*)(cea+2*e);
      a0+=v.x; a1+=v.y;
    }
    a0=wred_sum(a0); a1=wred_sum(a1);
    if(lane==0) w4[wv]=make_float2(a0,a1);
    __syncthreads();
    if(t==0){ float2 r=w4[0]; for(int i=1;i<4;i++){r.x+=w4[i].x; r.y+=w4[i].y;} partB[bb]=r; }
    for(int i=t;i<NC;i+=256) if(hist[i]) atomicAdd(&ccnt_dst[i],hist[i]);
  }
}

// ---------------- K3: fusion MFMA | prep_small | scan1 ----------------
// coefs layout: [4]=mean_ea0 [5]=mean_ea1 [6]=mean_cea0 [7]=mean_cea1
//               [8+h]=cgA0[h] [12+h]=cgA1[h] (h<4)
//               [16+l*2+h]=A0[l][h] [20+l*2+h]=A1[l][h] (l<2,h<2)
__global__ __launch_bounds__(256) void fus_scan_kernel(
    const float* __restrict__ item, const float* __restrict__ extra,
    const short* __restrict__ w1t, const float* __restrict__ b1,
    const short* __restrict__ w2t, const float* __restrict__ b2,
    float* __restrict__ X,
    const float2* __restrict__ partA, const float2* __restrict__ partB, int Ec,
    const float* __restrict__ cg_le, const float* __restrict__ cg_ae,
    const float* __restrict__ gat_le, const float* __restrict__ gat_ae,
    float* __restrict__ coefs,
    const int* __restrict__ cnt_dst, int* __restrict__ incl, int* __restrict__ bsum)
{
  __shared__ short As[128*40];
  __shared__ short Bs[128*40];
  __shared__ short Hs[128*136];
  __shared__ int ssc[256];
  const int tid = threadIdx.x;
  const int b = blockIdx.x;
  if(b < FUS_BLKS){
    const int blk = b;
    const int w = tid>>6, lane = tid&63, quad = lane>>4, l16 = lane&15;
    const int mw = w&1, nw = w>>1;

    v4f acc[4][4];
#pragma unroll
    for(int a=0;a<4;a++)
#pragma unroll
      for(int c=0;c<4;c++) acc[a][c] = (v4f){0.f,0.f,0.f,0.f};

    const int arow = tid>>3;
    const int aoff = (tid&7)*4;
    for(int s=0;s<KSTEPS;s++){
      const int k0 = s*32;
#pragma unroll
      for(int it=0;it<4;it++){
        int r = arow + it*32;
        int col = k0 + aoff;
        int gr = blk*128 + r; if(gr >= N_ITEMS) gr = N_ITEMS-1;
        float4 v = (col < DIM) ? *(const float4*)(item + (size_t)gr*DIM + col)
                               : *(const float4*)(extra + (size_t)gr*EXTRA_D + (col-DIM));
        short4 bv; bv.x=f2bf(v.x); bv.y=f2bf(v.y); bv.z=f2bf(v.z); bv.w=f2bf(v.w);
        *(short4*)&As[r*40 + aoff] = bv;
      }
#pragma unroll
      for(int it=0;it<2;it++){
        int idx = tid + it*256;
        int4 v = *(const int4*)(w1t + (size_t)s*4096 + idx*8);
        int n = idx>>2, kk = (idx&3)*8;
        *(int4*)&Bs[n*40 + kk] = v;
      }
      __syncthreads();
      short8 af[4], bf_[4];
#pragma unroll
      for(int i=0;i<4;i++){
        int m = mw*64 + i*16 + l16;
        af[i]  = *(const short8*)&As[m*40 + quad*8];
        int n = nw*64 + i*16 + l16;
        bf_[i] = *(const short8*)&Bs[n*40 + quad*8];
      }
#pragma unroll
      for(int mi=0;mi<4;mi++)
#pragma unroll
        for(int ni=0;ni<4;ni++)
          acc[mi][ni] = __builtin_amdgcn_mfma_f32_16x16x32_bf16(af[mi], bf_[ni], acc[mi][ni], 0,0,0);
      __syncthreads();
    }

#pragma unroll
    for(int ni=0;ni<4;ni++){
      int n = nw*64 + ni*16 + l16;
      float bias = b1[n];
#pragma unroll
      for(int mi=0;mi<4;mi++){
        int mbase = mw*64 + mi*16 + quad*4;
#pragma unroll
        for(int r=0;r<4;r++){
          float hv = fmaxf(acc[mi][ni][r] + bias, 0.f);
          Hs[(mbase+r)*136 + n] = f2bf(hv);
        }
      }
    }
    __syncthreads();

    v4f acc2[2][4];
#pragma unroll
    for(int a=0;a<2;a++)
#pragma unroll
      for(int c=0;c<4;c++) acc2[a][c] = (v4f){0.f,0.f,0.f,0.f};
#pragma unroll
    for(int ks=0;ks<4;ks++){
      short8 ha[2];
#pragma unroll
      for(int mi=0;mi<2;mi++){
        int m = w*32 + mi*16 + l16;
        ha[mi] = *(const short8*)&Hs[m*136 + ks*32 + quad*8];
      }
#pragma unroll
      for(int ni=0;ni<4;ni++){
        int c = ni*16 + l16;
        short8 wb = *(const short8*)(w2t + c*128 + ks*32 + quad*8);
#pragma unroll
        for(int mi=0;mi<2;mi++)
          acc2[mi][ni] = __builtin_amdgcn_mfma_f32_16x16x32_bf16(ha[mi], wb, acc2[mi][ni], 0,0,0);
      }
    }
#pragma unroll
    for(int ni=0;ni<4;ni++){
      int c = ni*16 + l16;
      float b2v = b2[c];
#pragma unroll
      for(int mi=0;mi<2;mi++){
        int mbase = w*32 + mi*16 + quad*4;
#pragma unroll
        for(int r=0;r<4;r++){
          int row = blk*128 + mbase + r;
          if(row < N_ITEMS) X[(size_t)(N_USERS+row)*64 + c] = acc2[mi][ni][r] + b2v;
        }
      }
    }
  } else if(b == FUS_BLKS){
    // prep_small
    int lane=tid&63; int wv=tid>>6;
    {
      int hh=wv;
      float v0 = cg_le[hh*64+lane]*cg_ae[hh*64+lane];
      float v1 = cg_le[256 + hh*64+lane]*cg_ae[hh*64+lane];
      v0=wred_sum(v0); v1=wred_sum(v1);
      if(lane==0){ coefs[8+hh]=v0; coefs[12+hh]=v1; }
    }
    {
      int l=wv>>1, hh=wv&1;
      float v0 = gat_le[l*256 + hh*64+lane]     * gat_ae[l*128+hh*64+lane];
      float v1 = gat_le[l*256 + 128 + hh*64+lane]* gat_ae[l*128+hh*64+lane];
      v0=wred_sum(v0); v1=wred_sum(v1);
      if(lane==0){ coefs[16+l*2+hh]=v0; coefs[20+l*2+hh]=v1; }
    }
    __syncthreads();
    if(wv==0){
      float2 v=partA[lane], v2=partA[64+lane];
      float sx=wred_sum(v.x+v2.x), sy=wred_sum(v.y+v2.y);
      if(lane==0){ coefs[4]=sx/(float)E_EDGES; coefs[5]=sy/(float)E_EDGES; }
    }
    if(wv==1){
      float2 v=partB[lane];
      float sx=wred_sum(v.x), sy=wred_sum(v.y);
      if(lane==0){ coefs[6]=sx/(float)Ec; coefs[7]=sy/(float)Ec; }
    }
  } else {
    // scan1: inclusive scan of (cnt_dst+1) per 1024-chunk, 256 thr x 4
    int sb = b-FUS_BLKS-1;
    int base = sb*1024 + tid*4;
    int a0=(base  <NTOT)?cnt_dst[base  ]+1:0;
    int a1=(base+1<NTOT)?cnt_dst[base+1]+1:0;
    int a2=(base+2<NTOT)?cnt_dst[base+2]+1:0;
    int a3=(base+3<NTOT)?cnt_dst[base+3]+1:0;
    int l1=a0+a1, l2=l1+a2, l3=l2+a3;
    ssc[tid]=l3; __syncthreads();
    for(int off=1;off<256;off<<=1){
      int v=(tid>=off)?ssc[tid-off]:0; __syncthreads();
      ssc[tid]+=v; __syncthreads();
    }
    int prev = tid? ssc[tid-1]:0;
    if(base  <NTOT) incl[base  ]=prev+a0;
    if(base+1<NTOT) incl[base+1]=prev+l1;
    if(base+2<NTOT) incl[base+2]=prev+l2;
    if(base+3<NTOT) incl[base+3]=prev+l3;
    if(tid==255) bsum[sb]=ssc[255];
  }
}

// ---------------- K4: scan3 (+dinv +self-loop slot) | cluster scan | xw ----------------
__global__ __launch_bounds__(256) void mid_kernel(
    const int* __restrict__ incl, const int* __restrict__ cnt,
    const int* __restrict__ bsum, int* __restrict__ offs, int* __restrict__ fillptr,
    const float* __restrict__ coefs, int2* __restrict__ slot2,
    const int* __restrict__ degI, float* __restrict__ dinv,
    const int* __restrict__ ccnt_dst, int* __restrict__ coffs, int* __restrict__ cfillp,
    const float* __restrict__ X, const float* __restrict__ gw, float* __restrict__ xw)
{
  __shared__ float Wl[64*64];
  __shared__ float rowb[4][64];
  __shared__ int sprev;
  const int b=blockIdx.x, t=threadIdx.x;
  if(b < SC3_BLKS){
    int blk10 = b>>2;
    if(t<64){
      int v = (t<blk10)? bsum[t] : 0;
      v = wred_sumi(v);
      if(t==0) sprev=v;
    }
    __syncthreads();
    unsigned pk = pack_bf2(coefs[4], coefs[5]);
    int i = b*256+t;
    if(i<NTOT){
      int c=cnt[i];
      int start = sprev + incl[i] - (c+1);
      offs[i]=start; fillptr[i]=start;
      slot2[start+c]=make_int2(i,(int)pk);
      dinv[i]=rsqrtf((float)(degI[i]+1));
    }
    if(i==0) offs[NTOT]=E_EDGES+NTOT;
  } else if(b == SC3_BLKS){
    if(t<64){
      int lane=t;
      int v0 = (2*lane<NC)? ccnt_dst[2*lane]:0;
      int v1 = (2*lane+1<NC)? ccnt_dst[2*lane+1]:0;
      int pair=v0+v1;
      int sc=pair;
#pragma unroll
      for(int o=1;o<64;o<<=1){ int t2=__shfl_up(sc,o,64); if(lane>=o) sc+=t2; }
      int excl = sc - pair;
      if(2*lane<NC){ coffs[2*lane]=excl; cfillp[2*lane]=excl; }
      if(2*lane+1<NC){ coffs[2*lane+1]=excl+v0; cfillp[2*lane+1]=excl+v0; }
      if(lane==63) coffs[NC]=sc;
    }
  } else {
    int bb=b-SC3_BLKS-1;
    const int lane=t&63, wv=t>>6;
    for(int i=t;i<4096;i+=256) Wl[i]=gw[i];
    __syncthreads();
    for(int r=bb*4+wv; r<NTOT; r+=1024*4){
      rowb[wv][lane]=X[(size_t)r*64+lane];
      float acc=0.f;
#pragma unroll 8
      for(int k=0;k<64;k++) acc+=rowb[wv][k]*Wl[k*64+lane];
      xw[(size_t)r*64+lane]=acc;
    }
  }
}

// ---------------- K5: fill (full-graph 8B slots | cluster edges) ----------------
__global__ __launch_bounds__(256) void fill_kernel(
    const int* __restrict__ fei, const float* __restrict__ fea,
    int* __restrict__ fillptr, int2* __restrict__ slot2,
    const int* __restrict__ cei, const float* __restrict__ cea, int Ec,
    int* __restrict__ cfillp, int* __restrict__ cslot_src, float2* __restrict__ cslot_ea)
{
  __shared__ int hist[NC];
  __shared__ int base[NC];
  const int b=blockIdx.x, t=threadIdx.x;
  if(b<FILL_BLKS){
    int e=b*256+t;
    if(e<E_EDGES){
      int dst=fei[E_EDGES+e], src=fei[e];
      int pos=atomicAdd(&fillptr[dst],1);
      float2 v=*(const float2*)(fea+2*e);
      slot2[pos]=make_int2(src,(int)pack_bf2(v.x,v.y));
    }
  } else {
    int bb=b-FILL_BLKS;
    const int chunk=(Ec+127)/128;
    const int beg=bb*chunk;
    const int end=min(beg+chunk,Ec);
    for(int i=t;i<NC;i+=256) hist[i]=0;
    __syncthreads();
    for(int e=beg+t;e<end;e+=256) atomicAdd(&hist[cei[Ec+e]],1);
    __syncthreads();
    for(int i=t;i<NC;i+=256){
      int h=hist[i];
      base[i] = h ? atomicAdd(&cfillp[i],h) : 0;
      hist[i]=0;
    }
    __syncthreads();
    for(int e=beg+t;e<end;e+=256){
      int d=cei[Ec+e];
      int pos = base[d] + atomicAdd(&hist[d],1);
      cslot_src[pos]=cei[e];
      cslot_ea[pos]=make_float2(cea[2*e],cea[2*e+1]);
    }
  }
}

// ---------------- K6: GCN aggregate (ballot-sparse) ----------------
__global__ __launch_bounds__(256) void gcn_agg_kernel(const float* __restrict__ X,
    const float* __restrict__ xw, const float* __restrict__ gcn_b,
    const int* __restrict__ offs, const int2* __restrict__ slot2, const int* __restrict__ ca,
    const float* __restrict__ dinv, const int* __restrict__ flag,
    float* __restrict__ Xc, float* __restrict__ psum){
  __shared__ float2 stg[4][64];
  int lane=threadIdx.x&63, wv=threadIdx.x>>6;
  int n=blockIdx.x*4+wv; if(n>=NTOT) return;
  int beg=offs[n], end=offs[n+1], myca=ca[n];
  float acc=0.f;
  for(int c0=beg;c0<end;c0+=64){
    int j=c0+lane;
    float coef=0.f; int s=0;
    if(j<end){
      s=slot2[j].x;
      if(ca[s]==myca) coef=dinv[s];
    }
    stg[wv][lane]=make_float2(__int_as_float(s),coef);
    unsigned long long bal=__ballot(coef!=0.f);
    while(bal){
      int k=__builtin_ctzll(bal); bal&=bal-1;
      float2 sc=stg[wv][k];
      acc += sc.y * xw[(size_t)__float_as_int(sc.x)*64+lane];
    }
  }
  float gout = dinv[n]*acc + gcn_b[lane];
  float xc = flag[myca] ? gout : X[(size_t)n*64+lane];
  Xc[(size_t)n*64+lane]=xc;
  atomicAdd(&psum[(size_t)(blockIdx.x&(PPART-1))*NC*64 + myca*64+lane], xc);
}

// ---------------- K7: cluster prep (pooled + xh_c + att) ----------------
__global__ __launch_bounds__(256) void cluster_prep_kernel(const float* __restrict__ psum,
    const int* __restrict__ ccnt, const float* __restrict__ cg_lin,
    const float* __restrict__ as_, const float* __restrict__ ad_,
    float* __restrict__ xh_c, float* __restrict__ asrc_c, float* __restrict__ adst_c){
  __shared__ float prow[64];
  const int c=blockIdx.x, t=threadIdx.x;
  if(t<64){
    float a=0.f;
#pragma unroll
    for(int p=0;p<PPART;p++) a += psum[(size_t)p*NC*64 + c*64 + t];
    prow[t]=a/fmaxf((float)ccnt[c],1.f);
  }
  __syncthreads();
  float acc=0.f;
#pragma unroll 8
  for(int k=0;k<64;k++) acc += prow[k]*cg_lin[k*256+t];
  xh_c[c*256+t]=acc;
  int lane=t&63, hh=t>>6;
  float s=wred_sum(acc*as_[hh*64+lane]);
  float d=wred_sum(acc*ad_[hh*64+lane]);
  if(lane==0){ asrc_c[c*4+hh]=s; adst_c[c*4+hh]=d; }
}
// ---------------- K8: cluster GAT aggregate ----------------
__global__ __launch_bounds__(256) void cluster_agg_kernel(
    const int* __restrict__ coffs, const int* __restrict__ cslot_src, const float2* __restrict__ cslot_ea,
    const float* __restrict__ asrc_c, const float* __restrict__ adst_c, const float* __restrict__ coefs,
    const float* __restrict__ xh_c, const float* __restrict__ cg_bias, float* __restrict__ cl_upd)
{
  __shared__ float sas[NC*4];
  __shared__ float sW[NC*4];
  __shared__ float ssum[4];
  __shared__ float red[4][64];
  const int c=blockIdx.x, t=threadIdx.x;
  for(int i=t;i<NC*4;i+=256){ sas[i]=asrc_c[i]; sW[i]=0.f; }
  __syncthreads();
  float ad[4], A0[4], A1[4];
#pragma unroll
  for(int h=0;h<4;h++){ ad[h]=adst_c[c*4+h]; A0[h]=coefs[8+h]; A1[h]=coefs[12+h]; }
  const int beg=coffs[c], end=coffs[c+1];
  for(int j=beg+t;j<end;j+=256){
    int s=cslot_src[j]; float2 e=cslot_ea[j];
#pragma unroll
    for(int h=0;h<4;h++){
      float al=lrelu(sas[s*4+h]+ad[h]+e.x*A0[h]+e.y*A1[h]);
      atomicAdd(&sW[s*4+h], __expf(al));
    }
  }
  if(t<4){
    float al=lrelu(sas[c*4+t]+ad[t]+coefs[6]*A0[t]+coefs[7]*A1[t]);
    atomicAdd(&sW[c*4+t], __expf(al));
  }
  __syncthreads();
  const int h=t>>6, lane=t&63;
  float p=0.f;
  if(lane<NC)    p += sW[lane*4+h];
  if(lane+64<NC) p += sW[(lane+64)*4+h];
  p=wred_sum(p);
  if(lane==0) ssum[h]=p+1e-16f;
  __syncthreads();
  float inv=1.f/ssum[h];
  float acc=0.f;
  for(int s=0;s<NC;s++) acc += sW[s*4+h]*xh_c[s*256+h*64+lane];
  red[h][lane]=acc*inv;
  __syncthreads();
  if(t<64) cl_upd[c*64+t]=0.25f*(red[0][t]+red[1][t]+red[2][t]+red[3][t])+cg_bias[t];
}

// ---------------- K9: GAT layer 0 xh (fused xcomb) ----------------
__global__ __launch_bounds__(256) void gat_xh0_kernel(const float* __restrict__ Xc,
    const float* __restrict__ cl_upd, const int* __restrict__ ca,
    const float* __restrict__ lin, const float* __restrict__ att_s, const float* __restrict__ att_d,
    float2* __restrict__ xh2, float* __restrict__ asrc, float* __restrict__ adst,
    float* __restrict__ Xa){
  __shared__ __align__(16) float Wl[64*128];
  __shared__ float rowb[4][64];
  int t=threadIdx.x;
  for(int i=t;i<8192;i+=256) Wl[i]=lin[i];
  __syncthreads();
  int lane=t&63, wv=t>>6;
  float as0=att_s[lane], as1=att_s[64+lane], ad0=att_d[lane], ad1=att_d[64+lane];
  for(int r=blockIdx.x*4+wv; r<NTOT; r+=gridDim.x*4){
    float xv = Xc[(size_t)r*64+lane] + cl_upd[ca[r]*64+lane];
    Xa[(size_t)r*64+lane]=xv;
    rowb[wv][lane]=xv;
    float x0=0.f,x1=0.f;
#pragma unroll 8
    for(int k=0;k<64;k++){ float q=rowb[wv][k]; x0+=q*Wl[k*128+lane]; x1+=q*Wl[k*128+64+lane]; }
    xh2[(size_t)r*64+lane]=make_float2(x0,x1);
    float p0=wred_sum(x0*as0);
    float p1=wred_sum(x1*as1);
    float q0=wred_sum(x0*ad0);
    float q1=wred_sum(x1*ad1);
    if(lane==0){ asrc[2*r]=p0; asrc[2*r+1]=p1; adst[2*r]=q0; adst[2*r+1]=q1; }
  }
}
// ---------------- K11: GAT layer 1 xh (fused GraphNorm+ELU of layer 0) ----------------
__global__ __launch_bounds__(256) void gat_xh1_kernel(const float* __restrict__ g,
    const float* __restrict__ Xres, const float* __restrict__ stats,
    const float* __restrict__ gnw, const float* __restrict__ gnb, const float* __restrict__ gnms,
    const float* __restrict__ lin, const float* __restrict__ att_s, const float* __restrict__ att_d,
    float2* __restrict__ xh2, float* __restrict__ asrc, float* __restrict__ adst,
    float* __restrict__ Xb){
  __shared__ __align__(16) float Wl[64*128];
  __shared__ float rowb[4][64];
  int t=threadIdx.x;
  for(int i=t;i<8192;i+=256) Wl[i]=lin[i];
  __syncthreads();
  int lane=t&63, wv=t>>6;
  const float invN = 1.f/(float)NTOT;
  float m=stats[lane]*invN;
  float mm=gnms[lane]*m;
  float gwv=rsqrtf(stats[64+lane]*invN - 2.f*mm*m + mm*mm + 1e-5f)*gnw[lane];
  float gbv=gnb[lane];
  float as0=att_s[lane], as1=att_s[64+lane], ad0=att_d[lane], ad1=att_d[64+lane];
  for(int r=blockIdx.x*4+wv; r<NTOT; r+=gridDim.x*4){
    float z=(g[(size_t)r*64+lane]-mm)*gwv+gbv + Xres[(size_t)r*64+lane];
    float xv = z>0.f? z : __expf(z)-1.f;
    Xb[(size_t)r*64+lane]=xv;
    rowb[wv][lane]=xv;
    float x0=0.f,x1=0.f;
#pragma unroll 8
    for(int k=0;k<64;k++){ float q=rowb[wv][k]; x0+=q*Wl[k*128+lane]; x1+=q*Wl[k*128+64+lane]; }
    xh2[(size_t)r*64+lane]=make_float2(x0,x1);
    float p0=wred_sum(x0*as0);
    float p1=wred_sum(x1*as1);
    float q0=wred_sum(x0*ad0);
    float q1=wred_sum(x1*ad1);
    if(lane==0){ asrc[2*r]=p0; asrc[2*r+1]=p1; adst[2*r]=q0; adst[2*r+1]=q1; }
  }
}

// ---------------- K10/K12: GAT aggregate (8B slots, x4-unrolled gather) ----------------
__global__ __launch_bounds__(256) void gat_agg_kernel(const float2* __restrict__ xh2,
    const float2* __restrict__ asrc, const float2* __restrict__ adst,
    const int* __restrict__ offs, const int2* __restrict__ slot2,
    const float* __restrict__ coefs, int layer, const float* __restrict__ bias,
    float* __restrict__ g){
  __shared__ float4 stg[4][64];
  int lane=threadIdx.x&63, wv=threadIdx.x>>6;
  int n=blockIdx.x*4+wv; if(n>=NTOT) return;
  float A00=coefs[16+layer*2+0], A01=coefs[16+layer*2+1];
  float A10=coefs[20+layer*2+0], A11=coefs[20+layer*2+1];
  int beg=offs[n], end=offs[n+1];
  float2 adn=adst[n];
  float s0=0.f,s1=0.f,acc0=0.f,acc1=0.f;
  for(int c0=beg;c0<end;c0+=64){
    int j=c0+lane;
    float ex0=0.f,ex1=0.f; int s=0;
    if(j<end){
      int2 sl=slot2[j];
      s=sl.x;
      unsigned p=(unsigned)sl.y;
      float e0=__uint_as_float(p<<16);
      float e1=__uint_as_float(p&0xffff0000u);
      float2 a=asrc[s];
      ex0=__expf(lrelu(a.x+adn.x+e0*A00+e1*A10));
      ex1=__expf(lrelu(a.y+adn.y+e0*A01+e1*A11));
    }
    s0+=ex0; s1+=ex1;
    stg[wv][lane]=make_float4(__int_as_float(s),ex0,ex1,0.f);
    int cnt=min(64,end-c0);
    int k=0;
    for(; k+4<=cnt; k+=4){
      float4 w0=stg[wv][k], w1=stg[wv][k+1], w2=stg[wv][k+2], w3=stg[wv][k+3];
      float2 x0=xh2[(size_t)__float_as_int(w0.x)*64+lane];
      float2 x1=xh2[(size_t)__float_as_int(w1.x)*64+lane];
      float2 x2=xh2[(size_t)__float_as_int(w2.x)*64+lane];
      float2 x3=xh2[(size_t)__float_as_int(w3.x)*64+lane];
      acc0 += w0.y*x0.x + w1.y*x1.x + w2.y*x2.x + w3.y*x3.x;
      acc1 += w0.z*x0.y + w1.z*x1.y + w2.z*x2.y + w3.z*x3.y;
    }
    for(; k<cnt; k++){
      float4 ws=stg[wv][k];
      float2 xv=xh2[(size_t)__float_as_int(ws.x)*64+lane];
      acc0 += ws.y*xv.x;
      acc1 += ws.z*xv.y;
    }
  }
  s0=wred_sum(s0); s1=wred_sum(s1);
  g[(size_t)n*64+lane]=0.5f*(acc0/(s0+1e-16f)+acc1/(s1+1e-16f))+bias[lane];
}
// GraphNorm stats: float4 loads, per-block shared reduce, direct global atomics (stats pre-zeroed)
__global__ __launch_bounds__(256) void stats_kernel(const float* __restrict__ g,
    float* __restrict__ stats){
  __shared__ float s1[64], s2[64];
  int t=threadIdx.x;
  if(t<64){s1[t]=0.f;s2[t]=0.f;}
  __syncthreads();
  float a0=0.f,a1=0.f,a2=0.f,a3=0.f,b0=0.f,b1=0.f,b2=0.f,b3=0.f;
  int i0=blockIdx.x*256+t;
  for(int i=i0;i<NTOT*16;i+=gridDim.x*256){
    float4 v=((const float4*)g)[i];
    a0+=v.x;a1+=v.y;a2+=v.z;a3+=v.w;
    b0+=v.x*v.x;b1+=v.y*v.y;b2+=v.z*v.z;b3+=v.w*v.w;
  }
  int d0=(i0&15)*4;
  atomicAdd(&s1[d0],a0); atomicAdd(&s1[d0+1],a1); atomicAdd(&s1[d0+2],a2); atomicAdd(&s1[d0+3],a3);
  atomicAdd(&s2[d0],b0); atomicAdd(&s2[d0+1],b1); atomicAdd(&s2[d0+2],b2); atomicAdd(&s2[d0+3],b3);
  __syncthreads();
  if(t<64) atomicAdd(&stats[t],s1[t]);
  else if(t<128) atomicAdd(&stats[t],s2[t-64]);
}
// final GraphNorm+ELU -> out (float4)
__global__ __launch_bounds__(256) void gnorm_elu_kernel(const float* __restrict__ g,
    const float* __restrict__ Xin, const float* __restrict__ stats,
    const float* __restrict__ gw, const float* __restrict__ gb, const float* __restrict__ gms,
    float* __restrict__ outp){
  const float invN = 1.f/(float)NTOT;
  int i0=blockIdx.x*256+threadIdx.x;
  int d0=(i0&15)*4;
  float mmv[4],gwv[4],gbv[4];
#pragma unroll
  for(int j=0;j<4;j++){
    int d=d0+j;
    float m=stats[d]*invN;
    float mm=gms[d]*m;
    mmv[j]=mm;
    gwv[j]=rsqrtf(stats[64+d]*invN-2.f*mm*m+mm*mm+1e-5f)*gw[d];
    gbv[j]=gb[d];
  }
  for(int i=i0;i<NTOT*16;i+=gridDim.x*256){
    float4 gv=((const float4*)g)[i];
    float4 xv=((const float4*)Xin)[i];
    float4 o; float z;
    z=(gv.x-mmv[0])*gwv[0]+gbv[0]+xv.x; o.x = z>0.f? z : __expf(z)-1.f;
    z=(gv.y-mmv[1])*gwv[1]+gbv[1]+xv.y; o.y = z>0.f? z : __expf(z)-1.f;
    z=(gv.z-mmv[2])*gwv[2]+gbv[2]+xv.z; o.z = z>0.f? z : __expf(z)-1.f;
    z=(gv.w-mmv[3])*gwv[3]+gbv[3]+xv.w; o.w = z>0.f? z : __expf(z)-1.f;
    ((float4*)outp)[i]=o;
  }
}

// ---------------- launch ----------------
extern "C" void kernel_launch(void* const* d_in, const int* in_sizes, int n_in,
                              void* d_out, int out_size, void* d_ws, size_t ws_size,
                              hipStream_t stream)
{
  const float* extra = (const float*)d_in[0];
  const float* user  = (const float*)d_in[1];
  const float* item  = (const float*)d_in[2];
  const float* fw1 = (const float*)d_in[3];
  const float* fb1 = (const float*)d_in[4];
  const float* fw2 = (const float*)d_in[5];
  const float* fb2 = (const float*)d_in[6];
  const float* fea = (const float*)d_in[7];
  const float* gcn_w = (const float*)d_in[8];
  const float* gcn_b = (const float*)d_in[9];
  const float* cg_lin = (const float*)d_in[10];
  const float* cg_as = (const float*)d_in[11];
  const float* cg_ad = (const float*)d_in[12];
  const float* cg_le = (const float*)d_in[13];
  const float* cg_ae = (const float*)d_in[14];
  const float* cg_bias = (const float*)d_in[15];
  const float* cea = (const float*)d_in[16];
  const float* gat_lin = (const float*)d_in[17];
  const float* gat_as = (const float*)d_in[18];
  const float* gat_ad = (const float*)d_in[19];
  const float* gat_le = (const float*)d_in[20];
  const float* gat_ae = (const float*)d_in[21];
  const float* gat_bias = (const float*)d_in[22];
  const float* gn_w = (const float*)d_in[23];
  const float* gn_b = (const float*)d_in[24];
  const float* gn_ms = (const float*)d_in[25];
  const int* fei = (const int*)d_in[26];
  const int* ca  = (const int*)d_in[27];
  const int* cei = (const int*)d_in[28];
  const int Ec = in_sizes[16]/2;
  float* outp = (float*)d_out;

  char* w = (char*)d_ws;
  auto alloc=[&](size_t b)->char*{ char* p=w; w += (b+255)&~(size_t)255; return p; };

  // zero region (single memset)
  char* z0 = w;
  int* cnt_dst = (int*)alloc((size_t)NTOT*4);
  int* degI = (int*)alloc((size_t)NTOT*4);
  int* clflag = (int*)alloc(NC*4);
  int* ccnt = (int*)alloc(NC*4);
  int* ccnt_dst = (int*)alloc(NC*4);
  float* psum = (float*)alloc((size_t)PPART*NC*64*4);
  float* stats0 = (float*)alloc(128*4);
  float* stats1 = (float*)alloc(128*4);
  size_t zbytes = (size_t)(w - z0);

  float2* partA = (float2*)alloc(128*8);
  float2* partB = (float2*)alloc(64*8);
  float* coefs = (float*)alloc(32*4);
  int* offs = (int*)alloc((size_t)(NTOT+1)*4);
  int* incl = (int*)alloc((size_t)NTOT*4);
  int* bsum = (int*)alloc(64*4);
  int* fillptr = (int*)alloc((size_t)NTOT*4);
  int2* slot2 = (int2*)alloc((size_t)(E_EDGES+NTOT)*8);
  int* coffs = (int*)alloc((size_t)(NC+1)*4);
  int* cfillp = (int*)alloc((size_t)NC*4);
  int* cslot_src = (int*)alloc((size_t)E_EDGES*4);
  float2* cslot_ea = (float2*)alloc((size_t)E_EDGES*8);
  float* dinv = (float*)alloc((size_t)NTOT*4);
  float* xh_c = (float*)alloc(NC*256*4);
  float* asrc_c = (float*)alloc(NC*4*4);
  float* adst_c = (float*)alloc(NC*4*4);
  float* cl_upd = (float*)alloc(NC*64*4);
  float* asrc = (float*)alloc((size_t)NTOT*2*4);
  float* adst = (float*)alloc((size_t)NTOT*2*4);
  short* w1t = (short*)alloc((size_t)KSTEPS*4096*2);
  short* w2t = (short*)alloc((size_t)64*128*2);
  float* bufA = (float*)alloc((size_t)NTOT*64*4);   // X, then g
  float* bufB = (float*)alloc((size_t)NTOT*64*4);   // Xc
  float* bufC = (float*)alloc((size_t)NTOT*64*4);   // xw, then Xb
  float* bufD = (float*)alloc((size_t)NTOT*64*4);   // Xa
  float* bufE = (float*)alloc((size_t)NTOT*128*4);  // xh2 (both layers)

  float* X  = bufA; float* g  = bufA;
  float* Xc = bufB;
  float* xw = bufC; float* Xb = bufC;
  float* Xa = bufD;
  float2* xh2 = (float2*)bufE;

  hipMemsetAsync(z0, 0, zbytes, stream);

  prep_all_kernel<<<PREP_GRID,256,0,stream>>>(user, X, fw1, w1t, fw2, w2t, ca, ccnt,
                                              fei, fea, cnt_dst, clflag, degI, partA,
                                              cei, cea, Ec, ccnt_dst, partB);
  fus_scan_kernel<<<FUS_BLKS+1+SCAN1_BLKS,256,0,stream>>>(item, extra, w1t, fb1, w2t, fb2, X,
                                              partA, partB, Ec, cg_le, cg_ae, gat_le, gat_ae, coefs,
                                              cnt_dst, incl, bsum);
  mid_kernel<<<SC3_BLKS+1+1024,256,0,stream>>>(incl, cnt_dst, bsum, offs, fillptr, coefs, slot2,
                                              degI, dinv, ccnt_dst, coffs, cfillp,
                                              X, gcn_w, xw);
  fill_kernel<<<FILL_BLKS+128,256,0,stream>>>(fei, fea, fillptr, slot2,
                                              cei, cea, Ec, cfillp, cslot_src, cslot_ea);

  gcn_agg_kernel<<<DEG_BLKS,256,0,stream>>>(X, xw, gcn_b, offs, slot2, ca, dinv, clflag, Xc, psum);
  cluster_prep_kernel<<<NC,256,0,stream>>>(psum, ccnt, cg_lin, cg_as, cg_ad, xh_c, asrc_c, adst_c);
  cluster_agg_kernel<<<NC,256,0,stream>>>(coffs, cslot_src, cslot_ea, asrc_c, adst_c, coefs,
                                          xh_c, cg_bias, cl_upd);

  // layer 0
  gat_xh0_kernel<<<1024,256,0,stream>>>(Xc, cl_upd, ca, gat_lin, gat_as, gat_ad,
                                        xh2, asrc, adst, Xa);
  gat_agg_kernel<<<DEG_BLKS,256,0,stream>>>(xh2, (const float2*)asrc, (const float2*)adst,
                                            offs, slot2, coefs, 0, gat_bias, g);
  stats_kernel<<<128,256,0,stream>>>(g, stats0);
  // layer 1
  gat_xh1_kernel<<<1024,256,0,stream>>>(g, Xa, stats0, gn_w, gn_b, gn_ms,
                                        gat_lin+64*128, gat_as+128, gat_ad+128,
                                        xh2, asrc, adst, Xb);
  gat_agg_kernel<<<DEG_BLKS,256,0,stream>>>(xh2, (const float2*)asrc, (const float2*)adst,
                                            offs, slot2, coefs, 1, gat_bias+64, g);
  stats_kernel<<<128,256,0,stream>>>(g, stats1);
  gnorm_elu_kernel<<<512,256,0,stream>>>(g, Xb, stats1, gn_w+64, gn_b+64, gn_ms+64, outp);
}

// Round 3
// 671.632 us; speedup vs baseline: 1.3190x; 1.0470x over previous
//
#include <hip/hip_runtime.h>
#include <hip/hip_bf16.h>

#define N_USERS 20000
#define N_ITEMS 30000
#define NTOT    50000
#define DIM     64
#define EXTRA_D 1152
#define E_EDGES 500000
#define NC      100
#define KTOT    1216
#define KSTEPS  38
#define PPART   16

// prep_all block ranges
#define B_COPY 1250
#define B_W1   608
#define B_W2   32
#define B_CC   64
#define B_FEI  1954
#define B_CEI  256
#define PREP_GRID (B_COPY+B_W1+B_W2+B_CC+B_FEI+B_CEI)

#define FUS_BLKS ((N_ITEMS+127)/128)     // 235
#define SCAN1_BLKS ((NTOT+1023)/1024)    // 49
#define SC3_BLKS ((NTOT+255)/256)        // 196
#define FILL_BLKS ((E_EDGES+255)/256)    // 1954
#define DEG_BLKS ((NTOT+3)/4)            // 12500

typedef __attribute__((ext_vector_type(8))) short short8;
typedef __attribute__((ext_vector_type(4))) float v4f;

// ---------------- helpers ----------------
__device__ __forceinline__ float wred_sum(float v){
#pragma unroll
  for(int o=32;o;o>>=1) v += __shfl_xor(v,o,64);
  return v;
}
__device__ __forceinline__ int wred_sumi(int v){
#pragma unroll
  for(int o=32;o;o>>=1) v += __shfl_xor(v,o,64);
  return v;
}
__device__ __forceinline__ float lrelu(float x){ return x>0.f? x : 0.2f*x; }
__device__ __forceinline__ short f2bf(float f){
  unsigned u=__float_as_uint(f);
  unsigned r=(u + 0x7FFFu + ((u>>16)&1u))>>16;
  return (short)r;
}
__device__ __forceinline__ unsigned pack_bf2(float x, float y){
  return (unsigned)(unsigned short)f2bf(x) | ((unsigned)(unsigned short)f2bf(y)<<16);
}

// ---------------- K2: prep_all ----------------
// user copy | w1 transpose->bf16 (coalesced reads) | w2 transpose->bf16 |
// cluster node hist | fei pass one-edge-per-thread (cnt_dst + clflag + intra-deg + fea sums) |
// cei pass 256 blocks (hist + cea sums)
__global__ __launch_bounds__(256) void prep_all_kernel(
    const float* __restrict__ u, float* __restrict__ X,
    const float* __restrict__ w1, short* __restrict__ w1t,
    const float* __restrict__ w2, short* __restrict__ w2t,
    const int* __restrict__ ca, int* __restrict__ ccnt,
    const int* __restrict__ fei, const float* __restrict__ fea,
    int* __restrict__ cnt_dst, int* __restrict__ clflag, int* __restrict__ degI,
    float2* __restrict__ partA,
    const int* __restrict__ cei, const float* __restrict__ cea, int Ec,
    int* __restrict__ ccnt_dst, float2* __restrict__ partB)
{
  __shared__ int hist[NC];
  __shared__ float2 w4[4];
  const int b=blockIdx.x, t=threadIdx.x;
  const int lane=t&63, wv=t>>6;
  if(b < B_COPY){
    int i = b*256+t;                       // 1250*256 == N_USERS*64/4 exactly
    ((float4*)X)[i] = ((const float4*)u)[i];
  } else if(b < B_COPY+B_W1){
    int i = (b-B_COPY)*256+t;              // 608*256 == 1216*128 exactly
    int row = i>>7, n = i&127;             // coalesced read w1[i] = w1[row*128+n]
    int s = row>>5, kk = row&31;
    w1t[s*4096 + n*32 + kk] = f2bf(w1[i]);
  } else if(b < B_COPY+B_W1+B_W2){
    int i = (b-B_COPY-B_W1)*256+t;         // 32*256 == 8192 exactly
    int n = i>>6, c = i&63;                // coalesced read w2[i] = w2[n*64+c]
    w2t[c*128 + n] = f2bf(w2[i]);
  } else if(b < B_COPY+B_W1+B_W2+B_CC){
    int bb = b-(B_COPY+B_W1+B_W2);
    for(int i=t;i<NC;i+=256) hist[i]=0;
    __syncthreads();
    for(int n=bb*256+t; n<NTOT; n+=B_CC*256) atomicAdd(&hist[ca[n]],1);
    __syncthreads();
    for(int i=t;i<NC;i+=256) if(hist[i]) atomicAdd(&ccnt[i],hist[i]);
  } else if(b < B_COPY+B_W1+B_W2+B_CC+B_FEI){
    int bb = b-(B_COPY+B_W1+B_W2+B_CC);
    int e = bb*256+t;
    float a0=0.f,a1=0.f;
    if(e<E_EDGES){
      int s=fei[e], d=fei[E_EDGES+e];
      atomicAdd(&cnt_dst[d],1);
      int cs=ca[s];
      if(cs==ca[d]){ clflag[cs]=1; atomicAdd(&degI[d],1); }
      float2 v=*(const float2*)(fea+2*e);
      a0=v.x; a1=v.y;
    }
    a0=wred_sum(a0); a1=wred_sum(a1);
    if(lane==0) w4[wv]=make_float2(a0,a1);
    __syncthreads();
    if(t==0){ float2 r=w4[0]; for(int i=1;i<4;i++){r.x+=w4[i].x; r.y+=w4[i].y;} partA[bb]=r; }
  } else {
    int bb = b-(B_COPY+B_W1+B_W2+B_CC+B_FEI);
    for(int i=t;i<NC;i+=256) hist[i]=0;
    __syncthreads();
    float a0=0.f,a1=0.f;
    for(int e=bb*256+t; e<Ec; e+=B_CEI*256){
      atomicAdd(&hist[cei[Ec+e]],1);
      float2 v=*(const float2*)(cea+2*e);
      a0+=v.x; a1+=v.y;
    }
    a0=wred_sum(a0); a1=wred_sum(a1);
    if(lane==0) w4[wv]=make_float2(a0,a1);
    __syncthreads();
    if(t==0){ float2 r=w4[0]; for(int i=1;i<4;i++){r.x+=w4[i].x; r.y+=w4[i].y;} partB[bb]=r; }
    for(int i=t;i<NC;i+=256) if(hist[i]) atomicAdd(&ccnt_dst[i],hist[i]);
  }
}

// ---------------- K3: fusion MFMA | prep_small | scan1 ----------------
// coefs layout: [4]=mean_ea0 [5]=mean_ea1 [6]=mean_cea0 [7]=mean_cea1
//               [8+h]=cgA0[h] [12+h]=cgA1[h] (h<4)
//               [16+l*2+h]=A0[l][h] [20+l*2+h]=A1[l][h] (l<2,h<2)
__global__ __launch_bounds__(256) void fus_scan_kernel(
    const float* __restrict__ item, const float* __restrict__ extra,
    const short* __restrict__ w1t, const float* __restrict__ b1,
    const short* __restrict__ w2t, const float* __restrict__ b2,
    float* __restrict__ X,
    const float2* __restrict__ partA, const float2* __restrict__ partB, int Ec,
    const float* __restrict__ cg_le, const float* __restrict__ cg_ae,
    const float* __restrict__ gat_le, const float* __restrict__ gat_ae,
    float* __restrict__ coefs,
    const int* __restrict__ cnt_dst, int* __restrict__ incl, int* __restrict__ bsum)
{
  __shared__ short As[128*40];
  __shared__ short Bs[128*40];
  __shared__ short Hs[128*136];
  __shared__ int ssc[256];
  const int tid = threadIdx.x;
  const int b = blockIdx.x;
  if(b < FUS_BLKS){
    const int blk = b;
    const int w = tid>>6, lane = tid&63, quad = lane>>4, l16 = lane&15;
    const int mw = w&1, nw = w>>1;

    v4f acc[4][4];
#pragma unroll
    for(int a=0;a<4;a++)
#pragma unroll
      for(int c=0;c<4;c++) acc[a][c] = (v4f){0.f,0.f,0.f,0.f};

    const int arow = tid>>3;
    const int aoff = (tid&7)*4;
    for(int s=0;s<KSTEPS;s++){
      const int k0 = s*32;
#pragma unroll
      for(int it=0;it<4;it++){
        int r = arow + it*32;
        int col = k0 + aoff;
        int gr = blk*128 + r; if(gr >= N_ITEMS) gr = N_ITEMS-1;
        float4 v = (col < DIM) ? *(const float4*)(item + (size_t)gr*DIM + col)
                               : *(const float4*)(extra + (size_t)gr*EXTRA_D + (col-DIM));
        short4 bv; bv.x=f2bf(v.x); bv.y=f2bf(v.y); bv.z=f2bf(v.z); bv.w=f2bf(v.w);
        *(short4*)&As[r*40 + aoff] = bv;
      }
#pragma unroll
      for(int it=0;it<2;it++){
        int idx = tid + it*256;
        int4 v = *(const int4*)(w1t + (size_t)s*4096 + idx*8);
        int n = idx>>2, kk = (idx&3)*8;
        *(int4*)&Bs[n*40 + kk] = v;
      }
      __syncthreads();
      short8 af[4], bf_[4];
#pragma unroll
      for(int i=0;i<4;i++){
        int m = mw*64 + i*16 + l16;
        af[i]  = *(const short8*)&As[m*40 + quad*8];
        int n = nw*64 + i*16 + l16;
        bf_[i] = *(const short8*)&Bs[n*40 + quad*8];
      }
#pragma unroll
      for(int mi=0;mi<4;mi++)
#pragma unroll
        for(int ni=0;ni<4;ni++)
          acc[mi][ni] = __builtin_amdgcn_mfma_f32_16x16x32_bf16(af[mi], bf_[ni], acc[mi][ni], 0,0,0);
      __syncthreads();
    }

#pragma unroll
    for(int ni=0;ni<4;ni++){
      int n = nw*64 + ni*16 + l16;
      float bias = b1[n];
#pragma unroll
      for(int mi=0;mi<4;mi++){
        int mbase = mw*64 + mi*16 + quad*4;
#pragma unroll
        for(int r=0;r<4;r++){
          float hv = fmaxf(acc[mi][ni][r] + bias, 0.f);
          Hs[(mbase+r)*136 + n] = f2bf(hv);
        }
      }
    }
    __syncthreads();

    v4f acc2[2][4];
#pragma unroll
    for(int a=0;a<2;a++)
#pragma unroll
      for(int c=0;c<4;c++) acc2[a][c] = (v4f){0.f,0.f,0.f,0.f};
#pragma unroll
    for(int ks=0;ks<4;ks++){
      short8 ha[2];
#pragma unroll
      for(int mi=0;mi<2;mi++){
        int m = w*32 + mi*16 + l16;
        ha[mi] = *(const short8*)&Hs[m*136 + ks*32 + quad*8];
      }
#pragma unroll
      for(int ni=0;ni<4;ni++){
        int c = ni*16 + l16;
        short8 wb = *(const short8*)(w2t + c*128 + ks*32 + quad*8);
#pragma unroll
        for(int mi=0;mi<2;mi++)
          acc2[mi][ni] = __builtin_amdgcn_mfma_f32_16x16x32_bf16(ha[mi], wb, acc2[mi][ni], 0,0,0);
      }
    }
#pragma unroll
    for(int ni=0;ni<4;ni++){
      int c = ni*16 + l16;
      float b2v = b2[c];
#pragma unroll
      for(int mi=0;mi<2;mi++){
        int mbase = w*32 + mi*16 + quad*4;
#pragma unroll
        for(int r=0;r<4;r++){
          int row = blk*128 + mbase + r;
          if(row < N_ITEMS) X[(size_t)(N_USERS+row)*64 + c] = acc2[mi][ni][r] + b2v;
        }
      }
    }
  } else if(b == FUS_BLKS){
    // prep_small
    int lane=tid&63; int wv=tid>>6;
    {
      int hh=wv;
      float v0 = cg_le[hh*64+lane]*cg_ae[hh*64+lane];
      float v1 = cg_le[256 + hh*64+lane]*cg_ae[hh*64+lane];
      v0=wred_sum(v0); v1=wred_sum(v1);
      if(lane==0){ coefs[8+hh]=v0; coefs[12+hh]=v1; }
    }
    {
      int l=wv>>1, hh=wv&1;
      float v0 = gat_le[l*256 + hh*64+lane]     * gat_ae[l*128+hh*64+lane];
      float v1 = gat_le[l*256 + 128 + hh*64+lane]* gat_ae[l*128+hh*64+lane];
      v0=wred_sum(v0); v1=wred_sum(v1);
      if(lane==0){ coefs[16+l*2+hh]=v0; coefs[20+l*2+hh]=v1; }
    }
    __syncthreads();
    if(wv==0){
      float sx=0.f, sy=0.f;
      for(int i=lane;i<B_FEI;i+=64){ float2 v=partA[i]; sx+=v.x; sy+=v.y; }
      sx=wred_sum(sx); sy=wred_sum(sy);
      if(lane==0){ coefs[4]=sx/(float)E_EDGES; coefs[5]=sy/(float)E_EDGES; }
    }
    if(wv==1){
      float sx=0.f, sy=0.f;
      for(int i=lane;i<B_CEI;i+=64){ float2 v=partB[i]; sx+=v.x; sy+=v.y; }
      sx=wred_sum(sx); sy=wred_sum(sy);
      if(lane==0){ coefs[6]=sx/(float)Ec; coefs[7]=sy/(float)Ec; }
    }
  } else {
    // scan1: inclusive scan of (cnt_dst+1) per 1024-chunk, 256 thr x 4
    int sb = b-FUS_BLKS-1;
    int base = sb*1024 + tid*4;
    int a0=(base  <NTOT)?cnt_dst[base  ]+1:0;
    int a1=(base+1<NTOT)?cnt_dst[base+1]+1:0;
    int a2=(base+2<NTOT)?cnt_dst[base+2]+1:0;
    int a3=(base+3<NTOT)?cnt_dst[base+3]+1:0;
    int l1=a0+a1, l2=l1+a2, l3=l2+a3;
    ssc[tid]=l3; __syncthreads();
    for(int off=1;off<256;off<<=1){
      int v=(tid>=off)?ssc[tid-off]:0; __syncthreads();
      ssc[tid]+=v; __syncthreads();
    }
    int prev = tid? ssc[tid-1]:0;
    if(base  <NTOT) incl[base  ]=prev+a0;
    if(base+1<NTOT) incl[base+1]=prev+l1;
    if(base+2<NTOT) incl[base+2]=prev+l2;
    if(base+3<NTOT) incl[base+3]=prev+l3;
    if(tid==255) bsum[sb]=ssc[255];
  }
}

// ---------------- K4: scan3 (+dinv +self-loop slot) | cluster scan | xw ----------------
__global__ __launch_bounds__(256) void mid_kernel(
    const int* __restrict__ incl, const int* __restrict__ cnt,
    const int* __restrict__ bsum, int* __restrict__ offs, int* __restrict__ fillptr,
    const float* __restrict__ coefs, int2* __restrict__ slot2,
    const int* __restrict__ degI, float* __restrict__ dinv,
    const int* __restrict__ ccnt_dst, int* __restrict__ coffs, int* __restrict__ cfillp,
    const float* __restrict__ X, const float* __restrict__ gw, float* __restrict__ xw)
{
  __shared__ float Wl[64*64];
  __shared__ float rowb[4][64];
  __shared__ int sprev;
  const int b=blockIdx.x, t=threadIdx.x;
  if(b < SC3_BLKS){
    int blk10 = b>>2;
    if(t<64){
      int v = (t<blk10)? bsum[t] : 0;
      v = wred_sumi(v);
      if(t==0) sprev=v;
    }
    __syncthreads();
    unsigned pk = pack_bf2(coefs[4], coefs[5]);
    int i = b*256+t;
    if(i<NTOT){
      int c=cnt[i];
      int start = sprev + incl[i] - (c+1);
      offs[i]=start; fillptr[i]=start;
      slot2[start+c]=make_int2(i,(int)pk);
      dinv[i]=rsqrtf((float)(degI[i]+1));
    }
    if(i==0) offs[NTOT]=E_EDGES+NTOT;
  } else if(b == SC3_BLKS){
    if(t<64){
      int lane=t;
      int v0 = (2*lane<NC)? ccnt_dst[2*lane]:0;
      int v1 = (2*lane+1<NC)? ccnt_dst[2*lane+1]:0;
      int pair=v0+v1;
      int sc=pair;
#pragma unroll
      for(int o=1;o<64;o<<=1){ int t2=__shfl_up(sc,o,64); if(lane>=o) sc+=t2; }
      int excl = sc - pair;
      if(2*lane<NC){ coffs[2*lane]=excl; cfillp[2*lane]=excl; }
      if(2*lane+1<NC){ coffs[2*lane+1]=excl+v0; cfillp[2*lane+1]=excl+v0; }
      if(lane==63) coffs[NC]=sc;
    }
  } else {
    int bb=b-SC3_BLKS-1;
    const int lane=t&63, wv=t>>6;
    for(int i=t;i<4096;i+=256) Wl[i]=gw[i];
    __syncthreads();
    for(int r=bb*4+wv; r<NTOT; r+=1024*4){
      rowb[wv][lane]=X[(size_t)r*64+lane];
      float acc=0.f;
#pragma unroll 8
      for(int k=0;k<64;k++) acc+=rowb[wv][k]*Wl[k*64+lane];
      xw[(size_t)r*64+lane]=acc;
    }
  }
}

// ---------------- K5: fill (full-graph 8B slots | cluster edges) ----------------
__global__ __launch_bounds__(256) void fill_kernel(
    const int* __restrict__ fei, const float* __restrict__ fea,
    int* __restrict__ fillptr, int2* __restrict__ slot2,
    const int* __restrict__ cei, const float* __restrict__ cea, int Ec,
    int* __restrict__ cfillp, int* __restrict__ cslot_src, float2* __restrict__ cslot_ea)
{
  __shared__ int hist[NC];
  __shared__ int base[NC];
  const int b=blockIdx.x, t=threadIdx.x;
  if(b<FILL_BLKS){
    int e=b*256+t;
    if(e<E_EDGES){
      int dst=fei[E_EDGES+e], src=fei[e];
      int pos=atomicAdd(&fillptr[dst],1);
      float2 v=*(const float2*)(fea+2*e);
      slot2[pos]=make_int2(src,(int)pack_bf2(v.x,v.y));
    }
  } else {
    int bb=b-FILL_BLKS;
    const int chunk=(Ec+127)/128;
    const int beg=bb*chunk;
    const int end=min(beg+chunk,Ec);
    for(int i=t;i<NC;i+=256) hist[i]=0;
    __syncthreads();
    for(int e=beg+t;e<end;e+=256) atomicAdd(&hist[cei[Ec+e]],1);
    __syncthreads();
    for(int i=t;i<NC;i+=256){
      int h=hist[i];
      base[i] = h ? atomicAdd(&cfillp[i],h) : 0;
      hist[i]=0;
    }
    __syncthreads();
    for(int e=beg+t;e<end;e+=256){
      int d=cei[Ec+e];
      int pos = base[d] + atomicAdd(&hist[d],1);
      cslot_src[pos]=cei[e];
      cslot_ea[pos]=make_float2(cea[2*e],cea[2*e+1]);
    }
  }
}

// ---------------- K6: GCN aggregate (ballot-sparse) ----------------
__global__ __launch_bounds__(256) void gcn_agg_kernel(const float* __restrict__ X,
    const float* __restrict__ xw, const float* __restrict__ gcn_b,
    const int* __restrict__ offs, const int2* __restrict__ slot2, const int* __restrict__ ca,
    const float* __restrict__ dinv, const int* __restrict__ flag,
    float* __restrict__ Xc, float* __restrict__ psum){
  __shared__ float2 stg[4][64];
  int lane=threadIdx.x&63, wv=threadIdx.x>>6;
  int n=blockIdx.x*4+wv; if(n>=NTOT) return;
  int beg=offs[n], end=offs[n+1], myca=ca[n];
  float acc=0.f;
  for(int c0=beg;c0<end;c0+=64){
    int j=c0+lane;
    float coef=0.f; int s=0;
    if(j<end){
      s=slot2[j].x;
      if(ca[s]==myca) coef=dinv[s];
    }
    stg[wv][lane]=make_float2(__int_as_float(s),coef);
    unsigned long long bal=__ballot(coef!=0.f);
    while(bal){
      int k=__builtin_ctzll(bal); bal&=bal-1;
      float2 sc=stg[wv][k];
      acc += sc.y * xw[(size_t)__float_as_int(sc.x)*64+lane];
    }
  }
  float gout = dinv[n]*acc + gcn_b[lane];
  float xc = flag[myca] ? gout : X[(size_t)n*64+lane];
  Xc[(size_t)n*64+lane]=xc;
  atomicAdd(&psum[(size_t)(blockIdx.x&(PPART-1))*NC*64 + myca*64+lane], xc);
}

// ---------------- K7: cluster prep (pooled + xh_c + att) ----------------
__global__ __launch_bounds__(256) void cluster_prep_kernel(const float* __restrict__ psum,
    const int* __restrict__ ccnt, const float* __restrict__ cg_lin,
    const float* __restrict__ as_, const float* __restrict__ ad_,
    float* __restrict__ xh_c, float* __restrict__ asrc_c, float* __restrict__ adst_c){
  __shared__ float prow[64];
  const int c=blockIdx.x, t=threadIdx.x;
  if(t<64){
    float a=0.f;
#pragma unroll
    for(int p=0;p<PPART;p++) a += psum[(size_t)p*NC*64 + c*64 + t];
    prow[t]=a/fmaxf((float)ccnt[c],1.f);
  }
  __syncthreads();
  float acc=0.f;
#pragma unroll 8
  for(int k=0;k<64;k++) acc += prow[k]*cg_lin[k*256+t];
  xh_c[c*256+t]=acc;
  int lane=t&63, hh=t>>6;
  float s=wred_sum(acc*as_[hh*64+lane]);
  float d=wred_sum(acc*ad_[hh*64+lane]);
  if(lane==0){ asrc_c[c*4+hh]=s; adst_c[c*4+hh]=d; }
}
// ---------------- K8: cluster GAT aggregate ----------------
__global__ __launch_bounds__(256) void cluster_agg_kernel(
    const int* __restrict__ coffs, const int* __restrict__ cslot_src, const float2* __restrict__ cslot_ea,
    const float* __restrict__ asrc_c, const float* __restrict__ adst_c, const float* __restrict__ coefs,
    const float* __restrict__ xh_c, const float* __restrict__ cg_bias, float* __restrict__ cl_upd)
{
  __shared__ float sas[NC*4];
  __shared__ float sW[NC*4];
  __shared__ float ssum[4];
  __shared__ float red[4][64];
  const int c=blockIdx.x, t=threadIdx.x;
  for(int i=t;i<NC*4;i+=256){ sas[i]=asrc_c[i]; sW[i]=0.f; }
  __syncthreads();
  float ad[4], A0[4], A1[4];
#pragma unroll
  for(int h=0;h<4;h++){ ad[h]=adst_c[c*4+h]; A0[h]=coefs[8+h]; A1[h]=coefs[12+h]; }
  const int beg=coffs[c], end=coffs[c+1];
  for(int j=beg+t;j<end;j+=256){
    int s=cslot_src[j]; float2 e=cslot_ea[j];
#pragma unroll
    for(int h=0;h<4;h++){
      float al=lrelu(sas[s*4+h]+ad[h]+e.x*A0[h]+e.y*A1[h]);
      atomicAdd(&sW[s*4+h], __expf(al));
    }
  }
  if(t<4){
    float al=lrelu(sas[c*4+t]+ad[t]+coefs[6]*A0[t]+coefs[7]*A1[t]);
    atomicAdd(&sW[c*4+t], __expf(al));
  }
  __syncthreads();
  const int h=t>>6, lane=t&63;
  float p=0.f;
  if(lane<NC)    p += sW[lane*4+h];
  if(lane+64<NC) p += sW[(lane+64)*4+h];
  p=wred_sum(p);
  if(lane==0) ssum[h]=p+1e-16f;
  __syncthreads();
  float inv=1.f/ssum[h];
  float acc=0.f;
  for(int s=0;s<NC;s++) acc += sW[s*4+h]*xh_c[s*256+h*64+lane];
  red[h][lane]=acc*inv;
  __syncthreads();
  if(t<64) cl_upd[c*64+t]=0.25f*(red[0][t]+red[1][t]+red[2][t]+red[3][t])+cg_bias[t];
}

// ---------------- K9: GAT layer 0 xh (fused xcomb) ----------------
__global__ __launch_bounds__(256) void gat_xh0_kernel(const float* __restrict__ Xc,
    const float* __restrict__ cl_upd, const int* __restrict__ ca,
    const float* __restrict__ lin, const float* __restrict__ att_s, const float* __restrict__ att_d,
    float2* __restrict__ xh2, float* __restrict__ asrc, float* __restrict__ adst,
    float* __restrict__ Xa){
  __shared__ __align__(16) float Wl[64*128];
  __shared__ float rowb[4][64];
  int t=threadIdx.x;
  for(int i=t;i<8192;i+=256) Wl[i]=lin[i];
  __syncthreads();
  int lane=t&63, wv=t>>6;
  float as0=att_s[lane], as1=att_s[64+lane], ad0=att_d[lane], ad1=att_d[64+lane];
  for(int r=blockIdx.x*4+wv; r<NTOT; r+=gridDim.x*4){
    float xv = Xc[(size_t)r*64+lane] + cl_upd[ca[r]*64+lane];
    Xa[(size_t)r*64+lane]=xv;
    rowb[wv][lane]=xv;
    float x0=0.f,x1=0.f;
#pragma unroll 8
    for(int k=0;k<64;k++){ float q=rowb[wv][k]; x0+=q*Wl[k*128+lane]; x1+=q*Wl[k*128+64+lane]; }
    xh2[(size_t)r*64+lane]=make_float2(x0,x1);
    float p0=wred_sum(x0*as0);
    float p1=wred_sum(x1*as1);
    float q0=wred_sum(x0*ad0);
    float q1=wred_sum(x1*ad1);
    if(lane==0){ asrc[2*r]=p0; asrc[2*r+1]=p1; adst[2*r]=q0; adst[2*r+1]=q1; }
  }
}
// ---------------- K11: GAT layer 1 xh (fused GraphNorm+ELU of layer 0) ----------------
__global__ __launch_bounds__(256) void gat_xh1_kernel(const float* __restrict__ g,
    const float* __restrict__ Xres, const float* __restrict__ stats,
    const float* __restrict__ gnw, const float* __restrict__ gnb, const float* __restrict__ gnms,
    const float* __restrict__ lin, const float* __restrict__ att_s, const float* __restrict__ att_d,
    float2* __restrict__ xh2, float* __restrict__ asrc, float* __restrict__ adst,
    float* __restrict__ Xb){
  __shared__ __align__(16) float Wl[64*128];
  __shared__ float rowb[4][64];
  int t=threadIdx.x;
  for(int i=t;i<8192;i+=256) Wl[i]=lin[i];
  __syncthreads();
  int lane=t&63, wv=t>>6;
  const float invN = 1.f/(float)NTOT;
  float m=stats[lane]*invN;
  float mm=gnms[lane]*m;
  float gwv=rsqrtf(stats[64+lane]*invN - 2.f*mm*m + mm*mm + 1e-5f)*gnw[lane];
  float gbv=gnb[lane];
  float as0=att_s[lane], as1=att_s[64+lane], ad0=att_d[lane], ad1=att_d[64+lane];
  for(int r=blockIdx.x*4+wv; r<NTOT; r+=gridDim.x*4){
    float z=(g[(size_t)r*64+lane]-mm)*gwv+gbv + Xres[(size_t)r*64+lane];
    float xv = z>0.f? z : __expf(z)-1.f;
    Xb[(size_t)r*64+lane]=xv;
    rowb[wv][lane]=xv;
    float x0=0.f,x1=0.f;
#pragma unroll 8
    for(int k=0;k<64;k++){ float q=rowb[wv][k]; x0+=q*Wl[k*128+lane]; x1+=q*Wl[k*128+64+lane]; }
    xh2[(size_t)r*64+lane]=make_float2(x0,x1);
    float p0=wred_sum(x0*as0);
    float p1=wred_sum(x1*as1);
    float q0=wred_sum(x0*ad0);
    float q1=wred_sum(x1*ad1);
    if(lane==0){ asrc[2*r]=p0; asrc[2*r+1]=p1; adst[2*r]=q0; adst[2*r+1]=q1; }
  }
}

// ---------------- K10/K12: GAT aggregate (8B slots, x4-unrolled gather) ----------------
__global__ __launch_bounds__(256) void gat_agg_kernel(const float2* __restrict__ xh2,
    const float2* __restrict__ asrc, const float2* __restrict__ adst,
    const int* __restrict__ offs, const int2* __restrict__ slot2,
    const float* __restrict__ coefs, int layer, const float* __restrict__ bias,
    float* __restrict__ g){
  __shared__ float4 stg[4][64];
  int lane=threadIdx.x&63, wv=threadIdx.x>>6;
  int n=blockIdx.x*4+wv; if(n>=NTOT) return;
  float A00=coefs[16+layer*2+0], A01=coefs[16+layer*2+1];
  float A10=coefs[20+layer*2+0], A11=coefs[20+layer*2+1];
  int beg=offs[n], end=offs[n+1];
  float2 adn=adst[n];
  float s0=0.f,s1=0.f,acc0=0.f,acc1=0.f;
  for(int c0=beg;c0<end;c0+=64){
    int j=c0+lane;
    float ex0=0.f,ex1=0.f; int s=0;
    if(j<end){
      int2 sl=slot2[j];
      s=sl.x;
      unsigned p=(unsigned)sl.y;
      float e0=__uint_as_float(p<<16);
      float e1=__uint_as_float(p&0xffff0000u);
      float2 a=asrc[s];
      ex0=__expf(lrelu(a.x+adn.x+e0*A00+e1*A10));
      ex1=__expf(lrelu(a.y+adn.y+e0*A01+e1*A11));
    }
    s0+=ex0; s1+=ex1;
    stg[wv][lane]=make_float4(__int_as_float(s),ex0,ex1,0.f);
    int cnt=min(64,end-c0);
    int k=0;
    for(; k+4<=cnt; k+=4){
      float4 w0=stg[wv][k], w1=stg[wv][k+1], w2=stg[wv][k+2], w3=stg[wv][k+3];
      float2 x0=xh2[(size_t)__float_as_int(w0.x)*64+lane];
      float2 x1=xh2[(size_t)__float_as_int(w1.x)*64+lane];
      float2 x2=xh2[(size_t)__float_as_int(w2.x)*64+lane];
      float2 x3=xh2[(size_t)__float_as_int(w3.x)*64+lane];
      acc0 += w0.y*x0.x + w1.y*x1.x + w2.y*x2.x + w3.y*x3.x;
      acc1 += w0.z*x0.y + w1.z*x1.y + w2.z*x2.y + w3.z*x3.y;
    }
    for(; k<cnt; k++){
      float4 ws=stg[wv][k];
      float2 xv=xh2[(size_t)__float_as_int(ws.x)*64+lane];
      acc0 += ws.y*xv.x;
      acc1 += ws.z*xv.y;
    }
  }
  s0=wred_sum(s0); s1=wred_sum(s1);
  g[(size_t)n*64+lane]=0.5f*(acc0/(s0+1e-16f)+acc1/(s1+1e-16f))+bias[lane];
}
// GraphNorm stats: float4 loads, per-block shared reduce, direct global atomics (stats pre-zeroed)
__global__ __launch_bounds__(256) void stats_kernel(const float* __restrict__ g,
    float* __restrict__ stats){
  __shared__ float s1[64], s2[64];
  int t=threadIdx.x;
  if(t<64){s1[t]=0.f;s2[t]=0.f;}
  __syncthreads();
  float a0=0.f,a1=0.f,a2=0.f,a3=0.f,b0=0.f,b1=0.f,b2=0.f,b3=0.f;
  int i0=blockIdx.x*256+t;
  for(int i=i0;i<NTOT*16;i+=gridDim.x*256){
    float4 v=((const float4*)g)[i];
    a0+=v.x;a1+=v.y;a2+=v.z;a3+=v.w;
    b0+=v.x*v.x;b1+=v.y*v.y;b2+=v.z*v.z;b3+=v.w*v.w;
  }
  int d0=(i0&15)*4;
  atomicAdd(&s1[d0],a0); atomicAdd(&s1[d0+1],a1); atomicAdd(&s1[d0+2],a2); atomicAdd(&s1[d0+3],a3);
  atomicAdd(&s2[d0],b0); atomicAdd(&s2[d0+1],b1); atomicAdd(&s2[d0+2],b2); atomicAdd(&s2[d0+3],b3);
  __syncthreads();
  if(t<64) atomicAdd(&stats[t],s1[t]);
  else if(t<128) atomicAdd(&stats[t],s2[t-64]);
}
// final GraphNorm+ELU -> out (float4)
__global__ __launch_bounds__(256) void gnorm_elu_kernel(const float* __restrict__ g,
    const float* __restrict__ Xin, const float* __restrict__ stats,
    const float* __restrict__ gw, const float* __restrict__ gb, const float* __restrict__ gms,
    float* __restrict__ outp){
  const float invN = 1.f/(float)NTOT;
  int i0=blockIdx.x*256+threadIdx.x;
  int d0=(i0&15)*4;
  float mmv[4],gwv[4],gbv[4];
#pragma unroll
  for(int j=0;j<4;j++){
    int d=d0+j;
    float m=stats[d]*invN;
    float mm=gms[d]*m;
    mmv[j]=mm;
    gwv[j]=rsqrtf(stats[64+d]*invN-2.f*mm*m+mm*mm+1e-5f)*gw[d];
    gbv[j]=gb[d];
  }
  for(int i=i0;i<NTOT*16;i+=gridDim.x*256){
    float4 gv=((const float4*)g)[i];
    float4 xv=((const float4*)Xin)[i];
    float4 o; float z;
    z=(gv.x-mmv[0])*gwv[0]+gbv[0]+xv.x; o.x = z>0.f? z : __expf(z)-1.f;
    z=(gv.y-mmv[1])*gwv[1]+gbv[1]+xv.y; o.y = z>0.f? z : __expf(z)-1.f;
    z=(gv.z-mmv[2])*gwv[2]+gbv[2]+xv.z; o.z = z>0.f? z : __expf(z)-1.f;
    z=(gv.w-mmv[3])*gwv[3]+gbv[3]+xv.w; o.w = z>0.f? z : __expf(z)-1.f;
    ((float4*)outp)[i]=o;
  }
}

// ---------------- launch ----------------
extern "C" void kernel_launch(void* const* d_in, const int* in_sizes, int n_in,
                              void* d_out, int out_size, void* d_ws, size_t ws_size,
                              hipStream_t stream)
{
  const float* extra = (const float*)d_in[0];
  const float* user  = (const float*)d_in[1];
  const float* item  = (const float*)d_in[2];
  const float* fw1 = (const float*)d_in[3];
  const float* fb1 = (const float*)d_in[4];
  const float* fw2 = (const float*)d_in[5];
  const float* fb2 = (const float*)d_in[6];
  const float* fea = (const float*)d_in[7];
  const float* gcn_w = (const float*)d_in[8];
  const float* gcn_b = (const float*)d_in[9];
  const float* cg_lin = (const float*)d_in[10];
  const float* cg_as = (const float*)d_in[11];
  const float* cg_ad = (const float*)d_in[12];
  const float* cg_le = (const float*)d_in[13];
  const float* cg_ae = (const float*)d_in[14];
  const float* cg_bias = (const float*)d_in[15];
  const float* cea = (const float*)d_in[16];
  const float* gat_lin = (const float*)d_in[17];
  const float* gat_as = (const float*)d_in[18];
  const float* gat_ad = (const float*)d_in[19];
  const float* gat_le = (const float*)d_in[20];
  const float* gat_ae = (const float*)d_in[21];
  const float* gat_bias = (const float*)d_in[22];
  const float* gn_w = (const float*)d_in[23];
  const float* gn_b = (const float*)d_in[24];
  const float* gn_ms = (const float*)d_in[25];
  const int* fei = (const int*)d_in[26];
  const int* ca  = (const int*)d_in[27];
  const int* cei = (const int*)d_in[28];
  const int Ec = in_sizes[16]/2;
  float* outp = (float*)d_out;

  char* w = (char*)d_ws;
  auto alloc=[&](size_t b)->char*{ char* p=w; w += (b+255)&~(size_t)255; return p; };

  // zero region (single memset)
  char* z0 = w;
  int* cnt_dst = (int*)alloc((size_t)NTOT*4);
  int* degI = (int*)alloc((size_t)NTOT*4);
  int* clflag = (int*)alloc(NC*4);
  int* ccnt = (int*)alloc(NC*4);
  int* ccnt_dst = (int*)alloc(NC*4);
  float* psum = (float*)alloc((size_t)PPART*NC*64*4);
  float* stats0 = (float*)alloc(128*4);
  float* stats1 = (float*)alloc(128*4);
  size_t zbytes = (size_t)(w - z0);

  float2* partA = (float2*)alloc(2048*8);
  float2* partB = (float2*)alloc(256*8);
  float* coefs = (float*)alloc(32*4);
  int* offs = (int*)alloc((size_t)(NTOT+1)*4);
  int* incl = (int*)alloc((size_t)NTOT*4);
  int* bsum = (int*)alloc(64*4);
  int* fillptr = (int*)alloc((size_t)NTOT*4);
  int2* slot2 = (int2*)alloc((size_t)(E_EDGES+NTOT)*8);
  int* coffs = (int*)alloc((size_t)(NC+1)*4);
  int* cfillp = (int*)alloc((size_t)NC*4);
  int* cslot_src = (int*)alloc((size_t)E_EDGES*4);
  float2* cslot_ea = (float2*)alloc((size_t)E_EDGES*8);
  float* dinv = (float*)alloc((size_t)NTOT*4);
  float* xh_c = (float*)alloc(NC*256*4);
  float* asrc_c = (float*)alloc(NC*4*4);
  float* adst_c = (float*)alloc(NC*4*4);
  float* cl_upd = (float*)alloc(NC*64*4);
  float* asrc = (float*)alloc((size_t)NTOT*2*4);
  float* adst = (float*)alloc((size_t)NTOT*2*4);
  short* w1t = (short*)alloc((size_t)KSTEPS*4096*2);
  short* w2t = (short*)alloc((size_t)64*128*2);
  float* bufA = (float*)alloc((size_t)NTOT*64*4);   // X, then g
  float* bufB = (float*)alloc((size_t)NTOT*64*4);   // Xc
  float* bufC = (float*)alloc((size_t)NTOT*64*4);   // xw, then Xb
  float* bufD = (float*)alloc((size_t)NTOT*64*4);   // Xa
  float* bufE = (float*)alloc((size_t)NTOT*128*4);  // xh2 (both layers)

  float* X  = bufA; float* g  = bufA;
  float* Xc = bufB;
  float* xw = bufC; float* Xb = bufC;
  float* Xa = bufD;
  float2* xh2 = (float2*)bufE;

  hipMemsetAsync(z0, 0, zbytes, stream);

  prep_all_kernel<<<PREP_GRID,256,0,stream>>>(user, X, fw1, w1t, fw2, w2t, ca, ccnt,
                                              fei, fea, cnt_dst, clflag, degI, partA,
                                              cei, cea, Ec, ccnt_dst, partB);
  fus_scan_kernel<<<FUS_BLKS+1+SCAN1_BLKS,256,0,stream>>>(item, extra, w1t, fb1, w2t, fb2, X,
                                              partA, partB, Ec, cg_le, cg_ae, gat_le, gat_ae, coefs,
                                              cnt_dst, incl, bsum);
  mid_kernel<<<SC3_BLKS+1+1024,256,0,stream>>>(incl, cnt_dst, bsum, offs, fillptr, coefs, slot2,
                                              degI, dinv, ccnt_dst, coffs, cfillp,
                                              X, gcn_w, xw);
  fill_kernel<<<FILL_BLKS+128,256,0,stream>>>(fei, fea, fillptr, slot2,
                                              cei, cea, Ec, cfillp, cslot_src, cslot_ea);

  gcn_agg_kernel<<<DEG_BLKS,256,0,stream>>>(X, xw, gcn_b, offs, slot2, ca, dinv, clflag, Xc, psum);
  cluster_prep_kernel<<<NC,256,0,stream>>>(psum, ccnt, cg_lin, cg_as, cg_ad, xh_c, asrc_c, adst_c);
  cluster_agg_kernel<<<NC,256,0,stream>>>(coffs, cslot_src, cslot_ea, asrc_c, adst_c, coefs,
                                          xh_c, cg_bias, cl_upd);

  // layer 0
  gat_xh0_kernel<<<1024,256,0,stream>>>(Xc, cl_upd, ca, gat_lin, gat_as, gat_ad,
                                        xh2, asrc, adst, Xa);
  gat_agg_kernel<<<DEG_BLKS,256,0,stream>>>(xh2, (const float2*)asrc, (const float2*)adst,
                                            offs, slot2, coefs, 0, gat_bias, g);
  stats_kernel<<<128,256,0,stream>>>(g, stats0);
  // layer 1
  gat_xh1_kernel<<<1024,256,0,stream>>>(g, Xa, stats0, gn_w, gn_b, gn_ms,
                                        gat_lin+64*128, gat_as+128, gat_ad+128,
                                        xh2, asrc, adst, Xb);
  gat_agg_kernel<<<DEG_BLKS,256,0,stream>>>(xh2, (const float2*)asrc, (const float2*)adst,
                                            offs, slot2, coefs, 1, gat_bias+64, g);
  stats_kernel<<<128,256,0,stream>>>(g, stats1);
  gnorm_elu_kernel<<<512,256,0,stream>>>(g, Xb, stats1, gn_w+64, gn_b+64, gn_ms+64, outp);
}